// Round 11
// baseline (89459.985 us; speedup 1.0000x reference)
//
#include <hip/hip_runtime.h>
#include <math.h>

#define NWG  256
#define NTHR 256
#define AGT __HIP_MEMORY_SCOPE_AGENT

// LDS float offsets
#define O_W2  0        // [16][1024]
#define O_W1  16384    // [16][512]
#define O_U   24576    // union: hstage [8][1024]  /  red [128][36] pre-folded
#define O_WX  33280    // [16][2]
#define O_B1  33312    // [16]
#define O_B2  33328    // [16]
#define O_WO  33344    // [4]
#define O_XS  33348    // [8][2]
#define O_GAT 33364    // [128]
#define O_C1  33492    // [32]
#define O_C2  33524    // [32]
#define O_HN  33556    // [32]
#define LDS_FLOATS 33600

union U64F2 { unsigned long long u; float f[2]; };

__global__ void ws_init_kernel(unsigned* flags) {
    for (int i = threadIdx.x; i < NWG * 16; i += blockDim.x) flags[i] = 0u;
}

__device__ __forceinline__ float sigm(float x) { return 1.0f / (1.0f + __expf(-x)); }
__device__ __forceinline__ float tanh_fast(float x) { return 2.0f / (1.0f + __expf(-2.0f * x)) - 1.0f; }

// Fence-free barrier, FULL poll: wave 0 (64 lanes) covers all 256 packed
// flags (u64 0..127). Works under PLAIN launch because 134KB LDS forces
// 1 block/CU and grid == CU count -> all 256 blocks co-resident; any block
// not yet dispatched just delays the spin, it cannot deadlock it.
__device__ __forceinline__ void gbar(unsigned* flags, int wg, int tid, unsigned ph) {
    __syncthreads();                                     // WG work complete
    asm volatile("s_waitcnt vmcnt(0)" ::: "memory");     // drain this wave's IC ops
    if (tid == 0)
        __hip_atomic_store(&flags[wg], ph, __ATOMIC_RELAXED, AGT);
    if (tid < 64) {                                      // 64 lanes x 2 u64 = 256 flags
        const unsigned long long* f64 = (const unsigned long long*)flags;
        bool done;
        do {
            unsigned long long v0 = __hip_atomic_load(&f64[tid],      __ATOMIC_RELAXED, AGT);
            unsigned long long v1 = __hip_atomic_load(&f64[tid + 64], __ATOMIC_RELAXED, AGT);
            done = ((unsigned)v0 >= ph) && ((unsigned)(v0 >> 32) >= ph) &&
                   ((unsigned)v1 >= ph) && ((unsigned)(v1 >> 32) >= ph);
            if (!__all(done)) __builtin_amdgcn_s_sleep(2);
        } while (!__all(done));
    }
    __syncthreads();
}

__global__ __launch_bounds__(NTHR, 1) void lstm_kernel(
    const float* __restrict__ xin,  const float* __restrict__ Wih1,
    const float* __restrict__ Whh1, const float* __restrict__ bih1,
    const float* __restrict__ bhh1, const float* __restrict__ Wih2,
    const float* __restrict__ Whh2, const float* __restrict__ bih2,
    const float* __restrict__ bhh2, const float* __restrict__ Wout,
    const float* __restrict__ bout, float* __restrict__ out,
    unsigned* __restrict__ flags, float* __restrict__ h1g,
    float* __restrict__ h2g, float* __restrict__ outred, int T)
{
    __shared__ float lds[LDS_FLOATS];
    const int tid = threadIdx.x;
    const int wg  = blockIdx.x;
    const int bh  = wg & 1;         // batch half: batches bh*8 .. bh*8+7
    const int jg  = wg >> 1;        // hidden-j group
    const int j0  = jg * 4;

    // ---- one-time: load weight slice into LDS ----
    for (int idx = tid; idx < 2048; idx += NTHR) {          // W1 = W_hh1 rows
        int r = idx >> 7, c4 = idx & 127;
        int grow = (r >> 2) * 512 + j0 + (r & 3);           // r = q*4+jj -> global row q*512+j
        *(float4*)&lds[O_W1 + r * 512 + c4 * 4] = *(const float4*)&Whh1[grow * 512 + c4 * 4];
    }
    for (int idx = tid; idx < 4096; idx += NTHR) {          // W2 = [W_ih2 | W_hh2] concat over K
        int r = idx >> 8, c4 = idx & 255;
        int grow = (r >> 2) * 512 + j0 + (r & 3);
        int k = c4 * 4;
        const float* src = (k < 512) ? &Wih2[grow * 512 + k] : &Whh2[grow * 512 + (k - 512)];
        *(float4*)&lds[O_W2 + r * 1024 + k] = *(const float4*)src;
    }
    if (tid < 32) {
        int r = tid >> 1, grow = (r >> 2) * 512 + j0 + (r & 3);
        lds[O_WX + tid] = Wih1[grow * 2 + (tid & 1)];
    }
    if (tid < 16) {
        int grow = (tid >> 2) * 512 + j0 + (tid & 3);
        lds[O_B1 + tid] = bih1[grow] + bhh1[grow];
        lds[O_B2 + tid] = bih2[grow] + bhh2[grow];
    }
    if (tid < 4) lds[O_WO + tid] = Wout[j0 + tid];
    if (tid < 32) { lds[O_C1 + tid] = 0.0f; lds[O_C2 + tid] = 0.0f; }
    const float bo = bout[0];
    __syncthreads();

    const int wv = tid >> 6;        // wave id -> row group (4 rows)
    const int ks = tid & 63;        // K-split lane
    unsigned ph = 0;

    for (int t = 0; t < T; ++t) {
        const int p = t & 1, pq = p ^ 1;

        // ================= phase A : layer 1 =================
        // stage h1_prev -> U[b][0..511]; BATCHED IC loads (validated R8)
        if (t == 0) {
            for (int idx = tid; idx < 1024; idx += NTHR) {
                int b = idx >> 7, c4 = idx & 127;
                *(float4*)&lds[O_U + b * 1024 + c4 * 4] = make_float4(0.f, 0.f, 0.f, 0.f);
            }
        } else {
            const unsigned long long* src = (const unsigned long long*)(h1g + pq * 8192);
            unsigned long long tmp[8];
            #pragma unroll
            for (int i = 0; i < 8; ++i) {
                int idx = tid + i * NTHR;
                int b = idx >> 8, pos = idx & 255;      // u64 units, 256 per batch row
                tmp[i] = __hip_atomic_load(&src[(bh * 8 + b) * 256 + pos],
                                           __ATOMIC_RELAXED, AGT);
            }
            #pragma unroll
            for (int i = 0; i < 8; ++i) {
                int idx = tid + i * NTHR;
                int b = idx >> 8, pos = idx & 255;
                *(unsigned long long*)&lds[O_U + b * 1024 + pos * 2] = tmp[i];
            }
        }
        if (tid < 16) {
            int b = tid >> 1, cm = tid & 1;
            lds[O_XS + tid] = xin[((bh * 8 + b) * (long)T + t) * 2 + cm];
        }
        __syncthreads();

        {   // gates: rows (4*wv..4*wv+3) x 8 batches, K=512 split over 64 lanes
            float acc[4][8];
            #pragma unroll
            for (int r = 0; r < 4; ++r)
                #pragma unroll
                for (int b = 0; b < 8; ++b) acc[r][b] = 0.0f;
            const float* Wb = &lds[O_W1 + wv * 4 * 512];
            #pragma unroll
            for (int c = 0; c < 2; ++c) {
                int k = ks * 4 + c * 256;
                float4 w0 = *(const float4*)&Wb[0 * 512 + k];
                float4 w1 = *(const float4*)&Wb[1 * 512 + k];
                float4 w2 = *(const float4*)&Wb[2 * 512 + k];
                float4 w3 = *(const float4*)&Wb[3 * 512 + k];
                #pragma unroll
                for (int b = 0; b < 8; ++b) {
                    float4 h = *(const float4*)&lds[O_U + b * 1024 + k];
                    acc[0][b] = fmaf(w0.x,h.x,fmaf(w0.y,h.y,fmaf(w0.z,h.z,fmaf(w0.w,h.w,acc[0][b]))));
                    acc[1][b] = fmaf(w1.x,h.x,fmaf(w1.y,h.y,fmaf(w1.z,h.z,fmaf(w1.w,h.w,acc[1][b]))));
                    acc[2][b] = fmaf(w2.x,h.x,fmaf(w2.y,h.y,fmaf(w2.z,h.z,fmaf(w2.w,h.w,acc[2][b]))));
                    acc[3][b] = fmaf(w3.x,h.x,fmaf(w3.y,h.y,fmaf(w3.z,h.z,fmaf(w3.w,h.w,acc[3][b]))));
                }
            }
            __syncthreads();            // done reading hstage; U becomes red[]
            // pre-fold k-pairs (ks, ks+32); only ks<32 writes red (stride 36)
            #pragma unroll
            for (int r = 0; r < 4; ++r)
                #pragma unroll
                for (int b = 0; b < 8; ++b) {
                    float s = acc[r][b] + __shfl_xor(acc[r][b], 32);
                    if (ks < 32)
                        lds[O_U + ((wv * 4 + r) * 8 + b) * 36 + ks] = s;
                }
        }
        __syncthreads();
        {   // K-reduce + bias + x-part (16 cols per half-reader)
            int o = tid >> 1, hf = tid & 1;
            const float* rr = &lds[O_U + o * 36 + hf * 16];
            float s = 0.0f;
            #pragma unroll
            for (int c = 0; c < 4; ++c) { float4 v = *(const float4*)&rr[c * 4]; s += v.x + v.y + v.z + v.w; }
            s += __shfl_xor(s, 1);
            if (hf == 0) {
                int r = o >> 3, b = o & 7;
                lds[O_GAT + o] = s + lds[O_B1 + r]
                               + lds[O_WX + r * 2]     * lds[O_XS + b * 2]
                               + lds[O_WX + r * 2 + 1] * lds[O_XS + b * 2 + 1];
            }
        }
        __syncthreads();
        if (tid < 32) {     // activations + cell update + publish h1 (IC atomic)
            int jj = tid >> 3, b = tid & 7;
            float gi = sigm(lds[O_GAT + (0 * 4 + jj) * 8 + b]);
            float gf = sigm(lds[O_GAT + (1 * 4 + jj) * 8 + b]);
            float gg = tanh_fast(lds[O_GAT + (2 * 4 + jj) * 8 + b]);
            float go = sigm(lds[O_GAT + (3 * 4 + jj) * 8 + b]);
            float c  = gf * lds[O_C1 + tid] + gi * gg;
            lds[O_C1 + tid] = c;
            __hip_atomic_store(&h1g[p * 8192 + (bh * 8 + b) * 512 + j0 + jj],
                               go * tanh_fast(c), __ATOMIC_RELAXED, AGT);
        }
        gbar(flags, wg, tid, ++ph);   // THE one barrier per step: h1_t broadcast

        // ================= phase B : layer 2 (no barrier after) =================
        // out duty: y_{t-1} from outred[pq] (written in B(t-1); bar_t between).
        if (wg < 16 && t > 0 && tid < 64) {
            const unsigned long long* row64 =
                (const unsigned long long*)(outred + pq * 2048 + wg * 128);
            U64F2 v; v.u = __hip_atomic_load(&row64[tid], __ATOMIC_RELAXED, AGT);
            float s = v.f[0] + v.f[1];
            #pragma unroll
            for (int off = 32; off >= 1; off >>= 1) s += __shfl_xor(s, off);
            if (tid == 0) out[wg * T + (t - 1)] = s + bo;
        }
        {   // stage [h1(t) | h2(t-1)]; BATCHED: 16 IC loads in flight, then LDS writes
            const unsigned long long* h1s = (const unsigned long long*)(h1g + p  * 8192);
            const unsigned long long* h2s = (const unsigned long long*)(h2g + pq * 8192);
            unsigned long long tmp[16];
            #pragma unroll
            for (int i = 0; i < 16; ++i) {
                int idx = tid + i * NTHR;
                int b = idx >> 9, pos = idx & 511;      // u64 units, 512 per [h1|h2] row
                if (pos < 256)
                    tmp[i] = __hip_atomic_load(&h1s[(bh * 8 + b) * 256 + pos], __ATOMIC_RELAXED, AGT);
                else if (t == 0)
                    tmp[i] = 0ull;
                else
                    tmp[i] = __hip_atomic_load(&h2s[(bh * 8 + b) * 256 + (pos - 256)], __ATOMIC_RELAXED, AGT);
            }
            #pragma unroll
            for (int i = 0; i < 16; ++i) {
                int idx = tid + i * NTHR;
                int b = idx >> 9, pos = idx & 511;
                *(unsigned long long*)&lds[O_U + b * 1024 + pos * 2] = tmp[i];
            }
        }
        __syncthreads();
        {
            float acc[4][8];
            #pragma unroll
            for (int r = 0; r < 4; ++r)
                #pragma unroll
                for (int b = 0; b < 8; ++b) acc[r][b] = 0.0f;
            const float* Wb = &lds[O_W2 + wv * 4 * 1024];
            #pragma unroll
            for (int c = 0; c < 4; ++c) {
                int k = ks * 4 + c * 256;
                float4 w0 = *(const float4*)&Wb[0 * 1024 + k];
                float4 w1 = *(const float4*)&Wb[1 * 1024 + k];
                float4 w2 = *(const float4*)&Wb[2 * 1024 + k];
                float4 w3 = *(const float4*)&Wb[3 * 1024 + k];
                #pragma unroll
                for (int b = 0; b < 8; ++b) {
                    float4 h = *(const float4*)&lds[O_U + b * 1024 + k];
                    acc[0][b] = fmaf(w0.x,h.x,fmaf(w0.y,h.y,fmaf(w0.z,h.z,fmaf(w0.w,h.w,acc[0][b]))));
                    acc[1][b] = fmaf(w1.x,h.x,fmaf(w1.y,h.y,fmaf(w1.z,h.z,fmaf(w1.w,h.w,acc[1][b]))));
                    acc[2][b] = fmaf(w2.x,h.x,fmaf(w2.y,h.y,fmaf(w2.z,h.z,fmaf(w2.w,h.w,acc[2][b]))));
                    acc[3][b] = fmaf(w3.x,h.x,fmaf(w3.y,h.y,fmaf(w3.z,h.z,fmaf(w3.w,h.w,acc[3][b]))));
                }
            }
            __syncthreads();
            #pragma unroll
            for (int r = 0; r < 4; ++r)
                #pragma unroll
                for (int b = 0; b < 8; ++b) {
                    float s = acc[r][b] + __shfl_xor(acc[r][b], 32);
                    if (ks < 32)
                        lds[O_U + ((wv * 4 + r) * 8 + b) * 36 + ks] = s;
                }
        }
        __syncthreads();
        {
            int o = tid >> 1, hf = tid & 1;
            const float* rr = &lds[O_U + o * 36 + hf * 16];
            float s = 0.0f;
            #pragma unroll
            for (int c = 0; c < 4; ++c) { float4 v = *(const float4*)&rr[c * 4]; s += v.x + v.y + v.z + v.w; }
            s += __shfl_xor(s, 1);
            if (hf == 0) {
                int r = o >> 3;
                lds[O_GAT + o] = s + lds[O_B2 + r];
            }
        }
        __syncthreads();
        if (tid < 32) {
            int jj = tid >> 3, b = tid & 7;
            float gi = sigm(lds[O_GAT + (0 * 4 + jj) * 8 + b]);
            float gf = sigm(lds[O_GAT + (1 * 4 + jj) * 8 + b]);
            float gg = tanh_fast(lds[O_GAT + (2 * 4 + jj) * 8 + b]);
            float go = sigm(lds[O_GAT + (3 * 4 + jj) * 8 + b]);
            float c  = gf * lds[O_C2 + tid] + gi * gg;
            lds[O_C2 + tid] = c;
            float h = go * tanh_fast(c);
            __hip_atomic_store(&h2g[p * 8192 + (bh * 8 + b) * 512 + j0 + jj],
                               h, __ATOMIC_RELAXED, AGT);
            lds[O_HN + tid] = lds[O_WO + jj] * h;      // product for W_out dot
        }
        __syncthreads();
        if (tid < 8) {      // per-batch partial of W_out dot for this j-group
            float pr = lds[O_HN + tid] + lds[O_HN + 8 + tid] + lds[O_HN + 16 + tid] + lds[O_HN + 24 + tid];
            __hip_atomic_store(&outred[p * 2048 + (bh * 8 + tid) * 128 + jg],
                               pr, __ATOMIC_RELAXED, AGT);
        }
        // no barrier here — next A-barrier (bar_{t+1}) covers B(t)'s publishes
    }

    // final barrier so the tail sees every WG's B(T-1) outred writes
    gbar(flags, wg, tid, ++ph);

    // tail: output for t = T-1
    if (wg < 16 && tid < 64) {
        const unsigned long long* row64 =
            (const unsigned long long*)(outred + ((T - 1) & 1) * 2048 + wg * 128);
        U64F2 v; v.u = __hip_atomic_load(&row64[tid], __ATOMIC_RELAXED, AGT);
        float s = v.f[0] + v.f[1];
        #pragma unroll
        for (int off = 32; off >= 1; off >>= 1) s += __shfl_xor(s, off);
        if (tid == 0) out[wg * T + (T - 1)] = s + bo;
    }
}

extern "C" void kernel_launch(void* const* d_in, const int* in_sizes, int n_in,
                              void* d_out, int out_size, void* d_ws, size_t ws_size,
                              hipStream_t stream) {
    const float* xin  = (const float*)d_in[0];
    const float* Wih1 = (const float*)d_in[1];
    const float* Whh1 = (const float*)d_in[2];
    const float* bih1 = (const float*)d_in[3];
    const float* bhh1 = (const float*)d_in[4];
    const float* Wih2 = (const float*)d_in[5];
    const float* Whh2 = (const float*)d_in[6];
    const float* bih2 = (const float*)d_in[7];
    const float* bhh2 = (const float*)d_in[8];
    const float* Wout = (const float*)d_in[9];
    const float* bout = (const float*)d_in[10];
    float* outp = (float*)d_out;
    int T = in_sizes[0] / 32;           // input is [16][T][2]

    unsigned* flags = (unsigned*)d_ws;                  // 256 packed u32 (region zeroed)
    float* h1g    = (float*)d_ws + 4096;                // [2][16][512]
    float* h2g    = h1g + 16384;                        // [2][16][512]
    float* outredp= h2g + 16384;                        // [2][16][128]

    hipLaunchKernelGGL(ws_init_kernel, dim3(1), dim3(256), 0, stream, flags);

    // PLAIN launch (not cooperative): co-residency is structural (1 block/CU
    // via 134KB LDS, grid == 256 == CU count). hipLaunchCooperativeKernel's
    // residency validation is the suspected silent-refusal path behind the
    // all-zero-output "ghost" failures (R2-R4, R9, R10 == R0-stub absmax).
    hipLaunchKernelGGL(lstm_kernel, dim3(NWG), dim3(NTHR), 0, stream,
                       xin, Wih1, Whh1, bih1, bhh1, Wih2, Whh2, bih2, bhh2,
                       Wout, bout, outp, flags, h1g, h2g, outredp, T);
}

// Round 12
// 66099.994 us; speedup vs baseline: 1.3534x; 1.3534x over previous
//
#include <hip/hip_runtime.h>
#include <math.h>

#define NWG  256
#define NTHR 256
#define AGT __HIP_MEMORY_SCOPE_AGENT

// LDS float offsets
#define O_W2  0        // [16][1024]  W2 = [W_ih2 | W_hh2] rows for this j-group
#define O_W1  16384    // [16][512]   W_hh1 rows
#define O_U   24576    // union: hstage [8][1024] / red [128][68] (8704 floats)
#define O_WX  33280    // [16][2]     W_ih1 (K=2)
#define O_B1  33312    // [16]
#define O_B2  33328    // [16]
#define O_WO  33344    // [4]
#define O_XS  33348    // [8][2]
#define O_G1  33364    // [128] layer-1 gates
#define O_G2  33492    // [128] layer-2 gates
#define O_C1  33620    // [32]
#define O_C2  33652    // [32]
#define O_HN  33684    // [32]
#define LDS_FLOATS 33720   // 134880 B <= 160 KiB

union U64F2 { unsigned long long u; float f[2]; };

__global__ void ws_init_kernel(unsigned* flags, float* h1g, float* h2g) {
    int i = blockIdx.x * blockDim.x + threadIdx.x;
    int n = gridDim.x * blockDim.x;
    for (int j = i; j < NWG; j += n) flags[j] = 0u;
    for (int j = i; j < 16384; j += n) { h1g[j] = 0.0f; h2g[j] = 0.0f; }
}

__device__ __forceinline__ float sigm(float x) { return 1.0f / (1.0f + __expf(-x)); }
__device__ __forceinline__ float tanh_fast(float x) { return 2.0f / (1.0f + __expf(-2.0f * x)) - 1.0f; }

// Fence-free barrier (R6-validated semantics), FULL 256-flag poll (R9 fix),
// plain-launch-safe: co-residency is structural (1 block/CU, grid == 256).
__device__ __forceinline__ void gbar(unsigned* flags, int wg, int tid, unsigned ph) {
    __syncthreads();
    asm volatile("s_waitcnt vmcnt(0)" ::: "memory");     // drain this wave's IC ops
    if (tid == 0)
        __hip_atomic_store(&flags[wg], ph, __ATOMIC_RELAXED, AGT);
    if (tid < 64) {
        const unsigned long long* f64 = (const unsigned long long*)flags;
        bool done;
        do {
            unsigned long long v0 = __hip_atomic_load(&f64[tid],      __ATOMIC_RELAXED, AGT);
            unsigned long long v1 = __hip_atomic_load(&f64[tid + 64], __ATOMIC_RELAXED, AGT);
            done = ((unsigned)v0 >= ph) && ((unsigned)(v0 >> 32) >= ph) &&
                   ((unsigned)v1 >= ph) && ((unsigned)(v1 >> 32) >= ph);
            if (!__all(done)) __builtin_amdgcn_s_sleep(2);
        } while (!__all(done));
    }
    __syncthreads();
}

__global__ __launch_bounds__(NTHR, 1) void lstm_kernel(
    const float* __restrict__ xin,  const float* __restrict__ Wih1,
    const float* __restrict__ Whh1, const float* __restrict__ bih1,
    const float* __restrict__ bhh1, const float* __restrict__ Wih2,
    const float* __restrict__ Whh2, const float* __restrict__ bih2,
    const float* __restrict__ bhh2, const float* __restrict__ Wout,
    const float* __restrict__ bout, float* __restrict__ out,
    unsigned* __restrict__ flags, float* __restrict__ h1g,
    float* __restrict__ h2g, float* __restrict__ outred, int T)
{
    __shared__ float lds[LDS_FLOATS];
    const int tid = threadIdx.x;
    const int wg  = blockIdx.x;
    const int bh  = wg & 1;         // batch half: batches bh*8 .. bh*8+7
    const int jg  = wg >> 1;        // hidden-j group
    const int j0  = jg * 4;

    // ---- one-time: load weight slice into LDS ----
    for (int idx = tid; idx < 2048; idx += NTHR) {          // W1 = W_hh1 rows
        int r = idx >> 7, c4 = idx & 127;
        int grow = (r >> 2) * 512 + j0 + (r & 3);           // local row q*4+jj -> global q*512+j
        *(float4*)&lds[O_W1 + r * 512 + c4 * 4] = *(const float4*)&Whh1[grow * 512 + c4 * 4];
    }
    for (int idx = tid; idx < 4096; idx += NTHR) {          // W2 = [W_ih2 | W_hh2]
        int r = idx >> 8, c4 = idx & 255;
        int grow = (r >> 2) * 512 + j0 + (r & 3);
        int k = c4 * 4;
        const float* src = (k < 512) ? &Wih2[grow * 512 + k] : &Whh2[grow * 512 + (k - 512)];
        *(float4*)&lds[O_W2 + r * 1024 + k] = *(const float4*)src;
    }
    if (tid < 32) {
        int r = tid >> 1, grow = (r >> 2) * 512 + j0 + (r & 3);
        lds[O_WX + tid] = Wih1[grow * 2 + (tid & 1)];
    }
    if (tid < 16) {
        int grow = (tid >> 2) * 512 + j0 + (tid & 3);
        lds[O_B1 + tid] = bih1[grow] + bhh1[grow];
        lds[O_B2 + tid] = bih2[grow] + bhh2[grow];
    }
    if (tid < 4) lds[O_WO + tid] = Wout[j0 + tid];
    if (tid < 32) { lds[O_C1 + tid] = 0.0f; lds[O_C2 + tid] = 0.0f; }
    const float bo = bout[0];
    __syncthreads();

    const int wv = tid >> 6;        // wave -> 4 gate rows
    const int ks = tid & 63;        // K-split lane
    unsigned ph = 0;

    // superstep s: compute h1_s (layer1, s<T) and h2_{s-1} (layer2, s>=1).
    // ONE barrier per superstep. h1g/h2g pre-zeroed => no s==0/1 special cases.
    for (int s = 0; s <= T; ++s) {
        const int p = s & 1, pq = p ^ 1;

        // ---- out duty: y_{s-2} from outred[pq] (written superstep s-1) ----
        if (wg < 16 && s >= 2 && tid < 64) {
            const unsigned long long* row64 =
                (const unsigned long long*)(outred + pq * 2048 + wg * 128);
            U64F2 v; v.u = __hip_atomic_load(&row64[tid], __ATOMIC_RELAXED, AGT);
            float sum = v.f[0] + v.f[1];
            #pragma unroll
            for (int off = 32; off >= 1; off >>= 1) sum += __shfl_xor(sum, off);
            if (tid == 0) out[wg * T + (s - 2)] = sum + bo;
        }

        // ---- stage U = [h1_{s-1} | h2_{s-2}]; BATCHED 16 IC loads in flight ----
        {
            const unsigned long long* h1s = (const unsigned long long*)(h1g + pq * 8192);
            const unsigned long long* h2s = (const unsigned long long*)(h2g + pq * 8192);
            unsigned long long tmp[16];
            #pragma unroll
            for (int i = 0; i < 16; ++i) {
                int idx = tid + i * NTHR;
                int b = idx >> 9, pos = idx & 511;      // u64 units, 512 per [h1|h2] row
                tmp[i] = (pos < 256)
                    ? __hip_atomic_load(&h1s[(bh * 8 + b) * 256 + pos],         __ATOMIC_RELAXED, AGT)
                    : __hip_atomic_load(&h2s[(bh * 8 + b) * 256 + (pos - 256)], __ATOMIC_RELAXED, AGT);
            }
            #pragma unroll
            for (int i = 0; i < 16; ++i) {
                int idx = tid + i * NTHR;
                int b = idx >> 9, pos = idx & 511;
                *(unsigned long long*)&lds[O_U + b * 1024 + pos * 2] = tmp[i];
            }
        }
        if (tid < 16 && s < T) {
            int b = tid >> 1, cm = tid & 1;
            lds[O_XS + tid] = xin[((bh * 8 + b) * (long)T + s) * 2 + cm];
        }
        __syncthreads();

        // ---- fused gate GEMMs: L2 (K=1024) + L1 (K=512), shared h loads ----
        float a1[4][8], a2[4][8];
        #pragma unroll
        for (int r = 0; r < 4; ++r)
            #pragma unroll
            for (int b = 0; b < 8; ++b) { a1[r][b] = 0.0f; a2[r][b] = 0.0f; }
        {
            const float* W2b = &lds[O_W2 + wv * 4096];
            const float* W1b = &lds[O_W1 + wv * 2048];
            #pragma unroll
            for (int c = 0; c < 4; ++c) {
                const int k = ks * 4 + c * 256;
                float4 u0 = *(const float4*)&W2b[k];
                float4 u1 = *(const float4*)&W2b[1024 + k];
                float4 u2 = *(const float4*)&W2b[2048 + k];
                float4 u3 = *(const float4*)&W2b[3072 + k];
                float4 w0, w1, w2, w3;
                if (c < 2) {
                    w0 = *(const float4*)&W1b[k];
                    w1 = *(const float4*)&W1b[512 + k];
                    w2 = *(const float4*)&W1b[1024 + k];
                    w3 = *(const float4*)&W1b[1536 + k];
                }
                #pragma unroll
                for (int b = 0; b < 8; ++b) {
                    float4 h = *(const float4*)&lds[O_U + b * 1024 + k];
                    a2[0][b] = fmaf(u0.x,h.x,fmaf(u0.y,h.y,fmaf(u0.z,h.z,fmaf(u0.w,h.w,a2[0][b]))));
                    a2[1][b] = fmaf(u1.x,h.x,fmaf(u1.y,h.y,fmaf(u1.z,h.z,fmaf(u1.w,h.w,a2[1][b]))));
                    a2[2][b] = fmaf(u2.x,h.x,fmaf(u2.y,h.y,fmaf(u2.z,h.z,fmaf(u2.w,h.w,a2[2][b]))));
                    a2[3][b] = fmaf(u3.x,h.x,fmaf(u3.y,h.y,fmaf(u3.z,h.z,fmaf(u3.w,h.w,a2[3][b]))));
                    if (c < 2) {
                        a1[0][b] = fmaf(w0.x,h.x,fmaf(w0.y,h.y,fmaf(w0.z,h.z,fmaf(w0.w,h.w,a1[0][b]))));
                        a1[1][b] = fmaf(w1.x,h.x,fmaf(w1.y,h.y,fmaf(w1.z,h.z,fmaf(w1.w,h.w,a1[1][b]))));
                        a1[2][b] = fmaf(w2.x,h.x,fmaf(w2.y,h.y,fmaf(w2.z,h.z,fmaf(w2.w,h.w,a1[2][b]))));
                        a1[3][b] = fmaf(w3.x,h.x,fmaf(w3.y,h.y,fmaf(w3.z,h.z,fmaf(w3.w,h.w,a1[3][b]))));
                    }
                }
            }
        }
        __syncthreads();                // staged-h reads done; U becomes red[]

        // ---- reduce L1 (stride 68: 16B-aligned float4 reads, 0-conflict proven) ----
        #pragma unroll
        for (int r = 0; r < 4; ++r)
            #pragma unroll
            for (int b = 0; b < 8; ++b)
                lds[O_U + ((wv * 4 + r) * 8 + b) * 68 + ks] = a1[r][b];
        __syncthreads();
        {
            int o = tid >> 1, hf = tid & 1;
            const float* rr = &lds[O_U + o * 68 + hf * 32];
            float sum = 0.0f;
            #pragma unroll
            for (int c = 0; c < 8; ++c) { float4 v = *(const float4*)&rr[c * 4]; sum += v.x + v.y + v.z + v.w; }
            sum += __shfl_xor(sum, 1);
            if (hf == 0) {
                int r = o >> 3, b = o & 7;
                lds[O_G1 + o] = sum + lds[O_B1 + r]
                              + lds[O_WX + r * 2]     * lds[O_XS + b * 2]
                              + lds[O_WX + r * 2 + 1] * lds[O_XS + b * 2 + 1];
            }
        }
        __syncthreads();

        // ---- reduce L2 ----
        #pragma unroll
        for (int r = 0; r < 4; ++r)
            #pragma unroll
            for (int b = 0; b < 8; ++b)
                lds[O_U + ((wv * 4 + r) * 8 + b) * 68 + ks] = a2[r][b];
        __syncthreads();
        {
            int o = tid >> 1, hf = tid & 1;
            const float* rr = &lds[O_U + o * 68 + hf * 32];
            float sum = 0.0f;
            #pragma unroll
            for (int c = 0; c < 8; ++c) { float4 v = *(const float4*)&rr[c * 4]; sum += v.x + v.y + v.z + v.w; }
            sum += __shfl_xor(sum, 1);
            if (hf == 0) lds[O_G2 + o] = sum + lds[O_B2 + (o >> 3)];
        }
        __syncthreads();

        // ---- activations + cell updates + coherent publish (wave 0) ----
        if (tid < 32) {
            if (s < T) {
                int jj = tid >> 3, b = tid & 7;
                float gi = sigm(lds[O_G1 + (0 * 4 + jj) * 8 + b]);
                float gf = sigm(lds[O_G1 + (1 * 4 + jj) * 8 + b]);
                float gg = tanh_fast(lds[O_G1 + (2 * 4 + jj) * 8 + b]);
                float go = sigm(lds[O_G1 + (3 * 4 + jj) * 8 + b]);
                float c  = gf * lds[O_C1 + tid] + gi * gg;
                lds[O_C1 + tid] = c;
                __hip_atomic_store(&h1g[p * 8192 + (bh * 8 + b) * 512 + j0 + jj],
                                   go * tanh_fast(c), __ATOMIC_RELAXED, AGT);
            }
        } else if (tid < 64) {
            if (s >= 1) {
                int t2 = tid - 32, jj = t2 >> 3, b = t2 & 7;
                float gi = sigm(lds[O_G2 + (0 * 4 + jj) * 8 + b]);
                float gf = sigm(lds[O_G2 + (1 * 4 + jj) * 8 + b]);
                float gg = tanh_fast(lds[O_G2 + (2 * 4 + jj) * 8 + b]);
                float go = sigm(lds[O_G2 + (3 * 4 + jj) * 8 + b]);
                float c  = gf * lds[O_C2 + t2] + gi * gg;
                lds[O_C2 + t2] = c;
                float h = go * tanh_fast(c);
                __hip_atomic_store(&h2g[p * 8192 + (bh * 8 + b) * 512 + j0 + jj],
                                   h, __ATOMIC_RELAXED, AGT);
                lds[O_HN + t2] = lds[O_WO + jj] * h;
            }
        }
        __syncthreads();   // HN written by lanes 32-63, read by lanes 0-7
        if (tid < 8 && s >= 1) {
            float pr = lds[O_HN + tid] + lds[O_HN + 8 + tid]
                     + lds[O_HN + 16 + tid] + lds[O_HN + 24 + tid];
            __hip_atomic_store(&outred[p * 2048 + (bh * 8 + tid) * 128 + jg],
                               pr, __ATOMIC_RELAXED, AGT);
        }

        gbar(flags, wg, tid, ++ph);     // THE one barrier per superstep
    }

    // tail: y_{T-1} (outred parity T&1, written at superstep s=T, covered by last bar)
    if (wg < 16 && tid < 64) {
        const unsigned long long* row64 =
            (const unsigned long long*)(outred + (T & 1) * 2048 + wg * 128);
        U64F2 v; v.u = __hip_atomic_load(&row64[tid], __ATOMIC_RELAXED, AGT);
        float sum = v.f[0] + v.f[1];
        #pragma unroll
        for (int off = 32; off >= 1; off >>= 1) sum += __shfl_xor(sum, off);
        if (tid == 0) out[wg * T + (T - 1)] = sum + bo;
    }
}

extern "C" void kernel_launch(void* const* d_in, const int* in_sizes, int n_in,
                              void* d_out, int out_size, void* d_ws, size_t ws_size,
                              hipStream_t stream) {
    const float* xin  = (const float*)d_in[0];
    const float* Wih1 = (const float*)d_in[1];
    const float* Whh1 = (const float*)d_in[2];
    const float* bih1 = (const float*)d_in[3];
    const float* bhh1 = (const float*)d_in[4];
    const float* Wih2 = (const float*)d_in[5];
    const float* Whh2 = (const float*)d_in[6];
    const float* bih2 = (const float*)d_in[7];
    const float* bhh2 = (const float*)d_in[8];
    const float* Wout = (const float*)d_in[9];
    const float* bout = (const float*)d_in[10];
    float* outp = (float*)d_out;
    int T = in_sizes[0] / 32;           // input is [16][T][2]

    unsigned* flags = (unsigned*)d_ws;                  // 256 packed u32
    float* h1g    = (float*)d_ws + 4096;                // [2][16][512] (zero-init)
    float* h2g    = h1g + 16384;                        // [2][16][512] (zero-init)
    float* outredp= h2g + 16384;                        // [2][16][128]

    hipLaunchKernelGGL(ws_init_kernel, dim3(32), dim3(256), 0, stream, flags, h1g, h2g);

    // PLAIN launch (R11-validated): cooperative launch was silently failing
    // intermittently (the absmax==2.136e-2 "ghost" == zeroed output == never ran).
    // Co-residency is structural: 134KB LDS -> 1 block/CU, grid == 256 == CUs.
    hipLaunchKernelGGL(lstm_kernel, dim3(NWG), dim3(NTHR), 0, stream,
                       xin, Wih1, Whh1, bih1, bhh1, Wih2, Whh2, bih2, bhh2,
                       Wout, bout, outp, flags, h1g, h2g, outredp, T);
}

// Round 13
// 63206.964 us; speedup vs baseline: 1.4154x; 1.0458x over previous
//
#include <hip/hip_runtime.h>
#include <math.h>

#define NWG  256
#define NTHR 256
#define AGT __HIP_MEMORY_SCOPE_AGENT

// LDS float offsets
#define O_W2  0        // [16][1024]  W2 = [W_ih2 | W_hh2] rows for this j-group
#define O_W1  16384    // [16][512]   W_hh1 rows
#define O_U   24576    // union: hstage [8][1024] / red [128][68] (8704 floats)
#define O_WX  33280    // [16][2]     W_ih1 (K=2)
#define O_B1  33312    // [16]
#define O_B2  33328    // [16]
#define O_WO  33344    // [4]
#define O_XS  33348    // [8][2]
#define O_G1  33364    // [128] layer-1 gates
#define O_G2  33492    // [128] layer-2 gates
#define O_C1  33620    // [32]
#define O_C2  33652    // [32]
#define O_HN  33684    // [32]
#define LDS_FLOATS 33720   // 134880 B <= 160 KiB

union U64F2 { unsigned long long u; float f[2]; };

__global__ void ws_init_kernel(unsigned* flags, float* h1g, float* h2g,
                               float* out, const float* bout, int n_out) {
    int i = blockIdx.x * blockDim.x + threadIdx.x;
    int n = gridDim.x * blockDim.x;
    float bo = bout[0];
    for (int j = i; j < NWG; j += n) flags[j] = 0u;
    for (int j = i; j < 16384; j += n) { h1g[j] = 0.0f; h2g[j] = 0.0f; }
    for (int j = i; j < n_out; j += n) out[j] = bo;   // duty atomicAdds onto b_out
}

__device__ __forceinline__ float sigm(float x) { return 1.0f / (1.0f + __expf(-x)); }
__device__ __forceinline__ float tanh_fast(float x) { return 2.0f / (1.0f + __expf(-2.0f * x)) - 1.0f; }

// Half-split fence-free barrier: after the duty spread, the two batch-halves
// (bh = wg&1) share NO data, so each WG syncs only its own 128 WGs.
// flags[0..127] = half 0 (even wg), flags[128..255] = half 1 (odd wg).
// 32 lanes x 2 u64 = 128 flags = FULL coverage of own half (no R6-R8 race).
__device__ __forceinline__ void gbar(unsigned* flags, int wg, int tid, unsigned ph) {
    __syncthreads();
    asm volatile("s_waitcnt vmcnt(0)" ::: "memory");     // drain this wave's IC ops
    const int half = wg & 1;
    if (tid == 0)
        __hip_atomic_store(&flags[(half << 7) + (wg >> 1)], ph, __ATOMIC_RELAXED, AGT);
    if (tid < 32) {
        const unsigned long long* f64 = (const unsigned long long*)flags + (half << 6);
        bool done;
        do {
            unsigned long long v0 = __hip_atomic_load(&f64[2 * tid],     __ATOMIC_RELAXED, AGT);
            unsigned long long v1 = __hip_atomic_load(&f64[2 * tid + 1], __ATOMIC_RELAXED, AGT);
            done = ((unsigned)v0 >= ph) && ((unsigned)(v0 >> 32) >= ph) &&
                   ((unsigned)v1 >= ph) && ((unsigned)(v1 >> 32) >= ph);
            if (!__all(done)) __builtin_amdgcn_s_sleep(2);
        } while (!__all(done));
    }
    __syncthreads();
}

__global__ __launch_bounds__(NTHR, 1) void lstm_kernel(
    const float* __restrict__ xin,  const float* __restrict__ Wih1,
    const float* __restrict__ Whh1, const float* __restrict__ bih1,
    const float* __restrict__ bhh1, const float* __restrict__ Wih2,
    const float* __restrict__ Whh2, const float* __restrict__ bih2,
    const float* __restrict__ bhh2, const float* __restrict__ Wout,
    const float* __restrict__ bout, float* __restrict__ out,
    unsigned* __restrict__ flags, float* __restrict__ h1g,
    float* __restrict__ h2g, float* __restrict__ outred, int T)
{
    __shared__ float lds[LDS_FLOATS];
    const int tid = threadIdx.x;
    const int wg  = blockIdx.x;
    const int bh  = wg & 1;         // batch half: batches bh*8 .. bh*8+7
    const int jg  = wg >> 1;        // hidden-j group
    const int j0  = jg * 4;
    const int bd  = bh * 8 + (jg & 7);  // duty batch (same half as this WG)
    const int jh  = jg >> 3;            // duty jg-octet

    // ---- one-time: load weight slice into LDS ----
    for (int idx = tid; idx < 2048; idx += NTHR) {          // W1 = W_hh1 rows
        int r = idx >> 7, c4 = idx & 127;
        int grow = (r >> 2) * 512 + j0 + (r & 3);           // local row q*4+jj -> global q*512+j
        *(float4*)&lds[O_W1 + r * 512 + c4 * 4] = *(const float4*)&Whh1[grow * 512 + c4 * 4];
    }
    for (int idx = tid; idx < 4096; idx += NTHR) {          // W2 = [W_ih2 | W_hh2]
        int r = idx >> 8, c4 = idx & 255;
        int grow = (r >> 2) * 512 + j0 + (r & 3);
        int k = c4 * 4;
        const float* src = (k < 512) ? &Wih2[grow * 512 + k] : &Whh2[grow * 512 + (k - 512)];
        *(float4*)&lds[O_W2 + r * 1024 + k] = *(const float4*)src;
    }
    if (tid < 32) {
        int r = tid >> 1, grow = (r >> 2) * 512 + j0 + (r & 3);
        lds[O_WX + tid] = Wih1[grow * 2 + (tid & 1)];
    }
    if (tid < 16) {
        int grow = (tid >> 2) * 512 + j0 + (tid & 3);
        lds[O_B1 + tid] = bih1[grow] + bhh1[grow];
        lds[O_B2 + tid] = bih2[grow] + bhh2[grow];
    }
    if (tid < 4) lds[O_WO + tid] = Wout[j0 + tid];
    if (tid < 32) { lds[O_C1 + tid] = 0.0f; lds[O_C2 + tid] = 0.0f; }
    __syncthreads();

    const int wv = tid >> 6;        // wave -> 4 gate rows
    const int ks = tid & 63;        // K-split lane
    unsigned ph = 0;

    // superstep s: compute h1_s (layer1, s<T) and h2_{s-1} (layer2, s>=1).
    // ONE half-barrier per superstep. h1g/h2g pre-zeroed.
    for (int s = 0; s <= T; ++s) {
        const int p = s & 1, pq = p ^ 1;

        // ---- out duty, SPREAD over all WGs: each sums 8 jg-partials of its
        // own-half batch bd and atomicAdds into out (pre-filled with b_out).
        // Loads overlap with the staging batch below; add is fire-and-forget.
        if (s >= 2 && tid == 0) {
            const unsigned long long* row64 =
                (const unsigned long long*)(outred + pq * 2048 + bd * 128 + jh * 8);
            U64F2 v0; v0.u = __hip_atomic_load(&row64[0], __ATOMIC_RELAXED, AGT);
            U64F2 v1; v1.u = __hip_atomic_load(&row64[1], __ATOMIC_RELAXED, AGT);
            U64F2 v2; v2.u = __hip_atomic_load(&row64[2], __ATOMIC_RELAXED, AGT);
            U64F2 v3; v3.u = __hip_atomic_load(&row64[3], __ATOMIC_RELAXED, AGT);
            float sum = (v0.f[0] + v0.f[1]) + (v1.f[0] + v1.f[1])
                      + (v2.f[0] + v2.f[1]) + (v3.f[0] + v3.f[1]);
            atomicAdd(&out[bd * T + (s - 2)], sum);
        }

        // ---- stage U = [h1_{s-1} | h2_{s-2}]; BATCHED 16 IC loads in flight ----
        {
            const unsigned long long* h1s = (const unsigned long long*)(h1g + pq * 8192);
            const unsigned long long* h2s = (const unsigned long long*)(h2g + pq * 8192);
            unsigned long long tmp[16];
            #pragma unroll
            for (int i = 0; i < 16; ++i) {
                int idx = tid + i * NTHR;
                int b = idx >> 9, pos = idx & 511;      // u64 units, 512 per [h1|h2] row
                tmp[i] = (pos < 256)
                    ? __hip_atomic_load(&h1s[(bh * 8 + b) * 256 + pos],         __ATOMIC_RELAXED, AGT)
                    : __hip_atomic_load(&h2s[(bh * 8 + b) * 256 + (pos - 256)], __ATOMIC_RELAXED, AGT);
            }
            #pragma unroll
            for (int i = 0; i < 16; ++i) {
                int idx = tid + i * NTHR;
                int b = idx >> 9, pos = idx & 511;
                *(unsigned long long*)&lds[O_U + b * 1024 + pos * 2] = tmp[i];
            }
        }
        if (tid < 16 && s < T) {
            int b = tid >> 1, cm = tid & 1;
            lds[O_XS + tid] = xin[((bh * 8 + b) * (long)T + s) * 2 + cm];
        }
        __syncthreads();

        // ---- fused gate GEMMs: L2 (K=1024) + L1 (K=512), shared h loads ----
        float a1[4][8], a2[4][8];
        #pragma unroll
        for (int r = 0; r < 4; ++r)
            #pragma unroll
            for (int b = 0; b < 8; ++b) { a1[r][b] = 0.0f; a2[r][b] = 0.0f; }
        {
            const float* W2b = &lds[O_W2 + wv * 4096];
            const float* W1b = &lds[O_W1 + wv * 2048];
            #pragma unroll
            for (int c = 0; c < 4; ++c) {
                const int k = ks * 4 + c * 256;
                float4 u0 = *(const float4*)&W2b[k];
                float4 u1 = *(const float4*)&W2b[1024 + k];
                float4 u2 = *(const float4*)&W2b[2048 + k];
                float4 u3 = *(const float4*)&W2b[3072 + k];
                float4 w0, w1, w2, w3;
                if (c < 2) {
                    w0 = *(const float4*)&W1b[k];
                    w1 = *(const float4*)&W1b[512 + k];
                    w2 = *(const float4*)&W1b[1024 + k];
                    w3 = *(const float4*)&W1b[1536 + k];
                }
                #pragma unroll
                for (int b = 0; b < 8; ++b) {
                    float4 h = *(const float4*)&lds[O_U + b * 1024 + k];
                    a2[0][b] = fmaf(u0.x,h.x,fmaf(u0.y,h.y,fmaf(u0.z,h.z,fmaf(u0.w,h.w,a2[0][b]))));
                    a2[1][b] = fmaf(u1.x,h.x,fmaf(u1.y,h.y,fmaf(u1.z,h.z,fmaf(u1.w,h.w,a2[1][b]))));
                    a2[2][b] = fmaf(u2.x,h.x,fmaf(u2.y,h.y,fmaf(u2.z,h.z,fmaf(u2.w,h.w,a2[2][b]))));
                    a2[3][b] = fmaf(u3.x,h.x,fmaf(u3.y,h.y,fmaf(u3.z,h.z,fmaf(u3.w,h.w,a2[3][b]))));
                    if (c < 2) {
                        a1[0][b] = fmaf(w0.x,h.x,fmaf(w0.y,h.y,fmaf(w0.z,h.z,fmaf(w0.w,h.w,a1[0][b]))));
                        a1[1][b] = fmaf(w1.x,h.x,fmaf(w1.y,h.y,fmaf(w1.z,h.z,fmaf(w1.w,h.w,a1[1][b]))));
                        a1[2][b] = fmaf(w2.x,h.x,fmaf(w2.y,h.y,fmaf(w2.z,h.z,fmaf(w2.w,h.w,a1[2][b]))));
                        a1[3][b] = fmaf(w3.x,h.x,fmaf(w3.y,h.y,fmaf(w3.z,h.z,fmaf(w3.w,h.w,a1[3][b]))));
                    }
                }
            }
        }
        __syncthreads();                // staged-h reads done; U becomes red[]

        // ---- reduce L1 (stride 68: 16B-aligned float4 reads, 0-conflict proven) ----
        #pragma unroll
        for (int r = 0; r < 4; ++r)
            #pragma unroll
            for (int b = 0; b < 8; ++b)
                lds[O_U + ((wv * 4 + r) * 8 + b) * 68 + ks] = a1[r][b];
        __syncthreads();
        {
            int o = tid >> 1, hf = tid & 1;
            const float* rr = &lds[O_U + o * 68 + hf * 32];
            float sum = 0.0f;
            #pragma unroll
            for (int c = 0; c < 8; ++c) { float4 v = *(const float4*)&rr[c * 4]; sum += v.x + v.y + v.z + v.w; }
            sum += __shfl_xor(sum, 1);
            if (hf == 0) {
                int r = o >> 3, b = o & 7;
                lds[O_G1 + o] = sum + lds[O_B1 + r]
                              + lds[O_WX + r * 2]     * lds[O_XS + b * 2]
                              + lds[O_WX + r * 2 + 1] * lds[O_XS + b * 2 + 1];
            }
        }
        __syncthreads();

        // ---- reduce L2 ----
        #pragma unroll
        for (int r = 0; r < 4; ++r)
            #pragma unroll
            for (int b = 0; b < 8; ++b)
                lds[O_U + ((wv * 4 + r) * 8 + b) * 68 + ks] = a2[r][b];
        __syncthreads();
        {
            int o = tid >> 1, hf = tid & 1;
            const float* rr = &lds[O_U + o * 68 + hf * 32];
            float sum = 0.0f;
            #pragma unroll
            for (int c = 0; c < 8; ++c) { float4 v = *(const float4*)&rr[c * 4]; sum += v.x + v.y + v.z + v.w; }
            sum += __shfl_xor(sum, 1);
            if (hf == 0) lds[O_G2 + o] = sum + lds[O_B2 + (o >> 3)];
        }
        __syncthreads();

        // ---- activations + cell updates + coherent publish (wave 0) ----
        if (tid < 32) {
            if (s < T) {
                int jj = tid >> 3, b = tid & 7;
                float gi = sigm(lds[O_G1 + (0 * 4 + jj) * 8 + b]);
                float gf = sigm(lds[O_G1 + (1 * 4 + jj) * 8 + b]);
                float gg = tanh_fast(lds[O_G1 + (2 * 4 + jj) * 8 + b]);
                float go = sigm(lds[O_G1 + (3 * 4 + jj) * 8 + b]);
                float c  = gf * lds[O_C1 + tid] + gi * gg;
                lds[O_C1 + tid] = c;
                __hip_atomic_store(&h1g[p * 8192 + (bh * 8 + b) * 512 + j0 + jj],
                                   go * tanh_fast(c), __ATOMIC_RELAXED, AGT);
            }
        } else if (tid < 64) {
            if (s >= 1) {
                int t2 = tid - 32, jj = t2 >> 3, b = t2 & 7;
                float gi = sigm(lds[O_G2 + (0 * 4 + jj) * 8 + b]);
                float gf = sigm(lds[O_G2 + (1 * 4 + jj) * 8 + b]);
                float gg = tanh_fast(lds[O_G2 + (2 * 4 + jj) * 8 + b]);
                float go = sigm(lds[O_G2 + (3 * 4 + jj) * 8 + b]);
                float c  = gf * lds[O_C2 + t2] + gi * gg;
                lds[O_C2 + t2] = c;
                float h = go * tanh_fast(c);
                __hip_atomic_store(&h2g[p * 8192 + (bh * 8 + b) * 512 + j0 + jj],
                                   h, __ATOMIC_RELAXED, AGT);
                lds[O_HN + t2] = lds[O_WO + jj] * h;
            }
        }
        __syncthreads();   // HN written by lanes 32-63, read by lanes 0-7
        if (tid < 8 && s >= 1) {
            float pr = lds[O_HN + tid] + lds[O_HN + 8 + tid]
                     + lds[O_HN + 16 + tid] + lds[O_HN + 24 + tid];
            __hip_atomic_store(&outred[p * 2048 + (bh * 8 + tid) * 128 + jg],
                               pr, __ATOMIC_RELAXED, AGT);
        }

        gbar(flags, wg, tid, ++ph);     // half-barrier, one per superstep
    }

    // tail: y_{T-1} partials (outred parity T&1, written at s=T, covered by last bar)
    if (tid == 0) {
        const unsigned long long* row64 =
            (const unsigned long long*)(outred + (T & 1) * 2048 + bd * 128 + jh * 8);
        U64F2 v0; v0.u = __hip_atomic_load(&row64[0], __ATOMIC_RELAXED, AGT);
        U64F2 v1; v1.u = __hip_atomic_load(&row64[1], __ATOMIC_RELAXED, AGT);
        U64F2 v2; v2.u = __hip_atomic_load(&row64[2], __ATOMIC_RELAXED, AGT);
        U64F2 v3; v3.u = __hip_atomic_load(&row64[3], __ATOMIC_RELAXED, AGT);
        float sum = (v0.f[0] + v0.f[1]) + (v1.f[0] + v1.f[1])
                  + (v2.f[0] + v2.f[1]) + (v3.f[0] + v3.f[1]);
        atomicAdd(&out[bd * T + (T - 1)], sum);
    }
}

extern "C" void kernel_launch(void* const* d_in, const int* in_sizes, int n_in,
                              void* d_out, int out_size, void* d_ws, size_t ws_size,
                              hipStream_t stream) {
    const float* xin  = (const float*)d_in[0];
    const float* Wih1 = (const float*)d_in[1];
    const float* Whh1 = (const float*)d_in[2];
    const float* bih1 = (const float*)d_in[3];
    const float* bhh1 = (const float*)d_in[4];
    const float* Wih2 = (const float*)d_in[5];
    const float* Whh2 = (const float*)d_in[6];
    const float* bih2 = (const float*)d_in[7];
    const float* bhh2 = (const float*)d_in[8];
    const float* Wout = (const float*)d_in[9];
    const float* bout = (const float*)d_in[10];
    float* outp = (float*)d_out;
    int T = in_sizes[0] / 32;           // input is [16][T][2]

    unsigned* flags = (unsigned*)d_ws;                  // [half0 x128 | half1 x128]
    float* h1g    = (float*)d_ws + 4096;                // [2][16][512] (zero-init)
    float* h2g    = h1g + 16384;                        // [2][16][512] (zero-init)
    float* outredp= h2g + 16384;                        // [2][16][128]

    hipLaunchKernelGGL(ws_init_kernel, dim3(64), dim3(256), 0, stream,
                       flags, h1g, h2g, outp, bout, out_size);

    // PLAIN launch (R11/R12-validated): cooperative launch silently flakes.
    // Co-residency is structural: 134KB LDS -> 1 block/CU, grid == 256 == CUs.
    hipLaunchKernelGGL(lstm_kernel, dim3(NWG), dim3(NTHR), 0, stream,
                       xin, Wih1, Whh1, bih1, bhh1, Wih2, Whh2, bih2, bhh2,
                       Wout, bout, outp, flags, h1g, h2g, outredp, T);
}

// Round 14
// 55967.407 us; speedup vs baseline: 1.5984x; 1.1294x over previous
//
#include <hip/hip_runtime.h>
#include <math.h>

#define NWG  256
#define NTHR 256
#define AGT __HIP_MEMORY_SCOPE_AGENT

// LDS float offsets
#define O_W2  0        // [16][1024]  W2 = [W_ih2 | W_hh2] rows for this j-group
#define O_W1  16384    // [16][512]   W_hh1 rows
#define O_U   24576    // union: hstage [8][1024] / red [128][68] (8704 floats)
#define O_WX  33280    // [16][2]     W_ih1 (K=2)
#define O_B1  33312    // [16]
#define O_B2  33328    // [16]
#define O_WO  33344    // [4]
#define O_XS  33348    // [8][2]
#define O_G1  33364    // [128] layer-1 gates
#define O_G2  33492    // [128] layer-2 gates
#define O_C1  33620    // [32]
#define O_C2  33652    // [32]
#define O_HN  33684    // [32]
#define LDS_FLOATS 33720   // 134880 B <= 160 KiB

union U64F2 { unsigned long long u; float f[2]; };

__global__ void ws_init_kernel(unsigned* flags, float* h1g, float* h2g,
                               float* out, const float* bout, int n_out) {
    int i = blockIdx.x * blockDim.x + threadIdx.x;
    int n = gridDim.x * blockDim.x;
    float bo = bout[0];
    for (int j = i; j < NWG; j += n) flags[j] = 0u;
    for (int j = i; j < 16384; j += n) { h1g[j] = 0.0f; h2g[j] = 0.0f; }
    for (int j = i; j < n_out; j += n) out[j] = bo;   // duty atomicAdds onto b_out
}

__device__ __forceinline__ float sigm(float x) { return 1.0f / (1.0f + __expf(-x)); }
__device__ __forceinline__ float tanh_fast(float x) { return 2.0f / (1.0f + __expf(-2.0f * x)) - 1.0f; }

// Half-split fence-free barrier (R13-validated): each WG syncs only its own
// 128 same-half WGs. flags[0..127] = half 0, flags[128..255] = half 1.
__device__ __forceinline__ void gbar(unsigned* flags, int wg, int tid, unsigned ph) {
    __syncthreads();
    asm volatile("s_waitcnt vmcnt(0)" ::: "memory");     // drain this wave's IC ops
    const int half = wg & 1;
    if (tid == 0)
        __hip_atomic_store(&flags[(half << 7) + (wg >> 1)], ph, __ATOMIC_RELAXED, AGT);
    if (tid < 32) {
        const unsigned long long* f64 = (const unsigned long long*)flags + (half << 6);
        bool done;
        do {
            unsigned long long v0 = __hip_atomic_load(&f64[2 * tid],     __ATOMIC_RELAXED, AGT);
            unsigned long long v1 = __hip_atomic_load(&f64[2 * tid + 1], __ATOMIC_RELAXED, AGT);
            done = ((unsigned)v0 >= ph) && ((unsigned)(v0 >> 32) >= ph) &&
                   ((unsigned)v1 >= ph) && ((unsigned)(v1 >> 32) >= ph);
            if (!__all(done)) __builtin_amdgcn_s_sleep(1);
        } while (!__all(done));
    }
    __syncthreads();
}

__global__ __launch_bounds__(NTHR, 1) void lstm_kernel(
    const float* __restrict__ xin,  const float* __restrict__ Wih1,
    const float* __restrict__ Whh1, const float* __restrict__ bih1,
    const float* __restrict__ bhh1, const float* __restrict__ Wih2,
    const float* __restrict__ Whh2, const float* __restrict__ bih2,
    const float* __restrict__ bhh2, const float* __restrict__ Wout,
    const float* __restrict__ bout, float* __restrict__ out,
    unsigned* __restrict__ flags, float* __restrict__ h1g,
    float* __restrict__ h2g, float* __restrict__ outred, int T)
{
    __shared__ float lds[LDS_FLOATS];
    const int tid = threadIdx.x;
    const int wg  = blockIdx.x;
    const int bh  = wg & 1;         // batch half: batches bh*8 .. bh*8+7
    const int jg  = wg >> 1;        // hidden-j group
    const int j0  = jg * 4;
    const int bd  = bh * 8 + (jg & 7);  // duty batch (same half as this WG)
    const int jh  = jg >> 3;            // duty jg-octet

    // ---- one-time: load weight slice into LDS ----
    for (int idx = tid; idx < 2048; idx += NTHR) {          // W1 = W_hh1 rows
        int r = idx >> 7, c4 = idx & 127;
        int grow = (r >> 2) * 512 + j0 + (r & 3);           // local row q*4+jj -> global q*512+j
        *(float4*)&lds[O_W1 + r * 512 + c4 * 4] = *(const float4*)&Whh1[grow * 512 + c4 * 4];
    }
    for (int idx = tid; idx < 4096; idx += NTHR) {          // W2 = [W_ih2 | W_hh2]
        int r = idx >> 8, c4 = idx & 255;
        int grow = (r >> 2) * 512 + j0 + (r & 3);
        int k = c4 * 4;
        const float* src = (k < 512) ? &Wih2[grow * 512 + k] : &Whh2[grow * 512 + (k - 512)];
        *(float4*)&lds[O_W2 + r * 1024 + k] = *(const float4*)src;
    }
    if (tid < 32) {
        int r = tid >> 1, grow = (r >> 2) * 512 + j0 + (r & 3);
        lds[O_WX + tid] = Wih1[grow * 2 + (tid & 1)];
    }
    if (tid < 16) {
        int grow = (tid >> 2) * 512 + j0 + (tid & 3);
        lds[O_B1 + tid] = bih1[grow] + bhh1[grow];
        lds[O_B2 + tid] = bih2[grow] + bhh2[grow];
    }
    if (tid < 4) lds[O_WO + tid] = Wout[j0 + tid];
    if (tid < 32) { lds[O_C1 + tid] = 0.0f; lds[O_C2 + tid] = 0.0f; }
    __syncthreads();

    const int wv = tid >> 6;        // wave -> 4 gate rows
    const int ks = tid & 63;        // K-split lane
    unsigned ph = 0;

    // superstep s: compute h1_s (layer1, s<T) and h2_{s-1} (layer2, s>=1).
    // ONE half-barrier per superstep. h1g/h2g pre-zeroed.
    for (int s = 0; s <= T; ++s) {
        const int p = s & 1, pq = p ^ 1;

        // ---- out duty, spread over all WGs (atomicAdd onto b_out-prefilled out) ----
        if (s >= 2 && tid == 0) {
            const unsigned long long* row64 =
                (const unsigned long long*)(outred + pq * 2048 + bd * 128 + jh * 8);
            U64F2 v0; v0.u = __hip_atomic_load(&row64[0], __ATOMIC_RELAXED, AGT);
            U64F2 v1; v1.u = __hip_atomic_load(&row64[1], __ATOMIC_RELAXED, AGT);
            U64F2 v2; v2.u = __hip_atomic_load(&row64[2], __ATOMIC_RELAXED, AGT);
            U64F2 v3; v3.u = __hip_atomic_load(&row64[3], __ATOMIC_RELAXED, AGT);
            float sum = (v0.f[0] + v0.f[1]) + (v1.f[0] + v1.f[1])
                      + (v2.f[0] + v2.f[1]) + (v3.f[0] + v3.f[1]);
            atomicAdd(&out[bd * T + (s - 2)], sum);
        }

        // ---- stage U = [h1_{s-1} | h2_{s-2}] via COALESCED coherent loads ----
        // global_load_dwordx4 sc0 sc1 reads through L1/L2 to the coherence
        // point (same semantics as relaxed-agent atomic loads, but 16B-wide
        // and lane-coalesced: 8x fewer IC transactions than atomic u64).
        // Thread tid, iter i: src = base + i*512 + tid*4, dst = U + i*1024 + tid*4.
        // tid<128 -> h1 region; tid>=128 -> h2 region (wave-uniform split).
        {
            const float* srcb = (tid < 128)
                ? (h1g + pq * 8192 + (bh * 8) * 512 + tid * 4)
                : (h2g + pq * 8192 + (bh * 8) * 512 + (tid - 128) * 4);
            float4 r0, r1, r2, r3, r4, r5, r6, r7;
            asm volatile(
                "global_load_dwordx4 %0, %8, off sc0 sc1\n\t"
                "global_load_dwordx4 %1, %9, off sc0 sc1\n\t"
                "global_load_dwordx4 %2, %10, off sc0 sc1\n\t"
                "global_load_dwordx4 %3, %11, off sc0 sc1\n\t"
                "global_load_dwordx4 %4, %12, off sc0 sc1\n\t"
                "global_load_dwordx4 %5, %13, off sc0 sc1\n\t"
                "global_load_dwordx4 %6, %14, off sc0 sc1\n\t"
                "global_load_dwordx4 %7, %15, off sc0 sc1\n\t"
                "s_waitcnt vmcnt(0)"
                : "=&v"(r0), "=&v"(r1), "=&v"(r2), "=&v"(r3),
                  "=&v"(r4), "=&v"(r5), "=&v"(r6), "=&v"(r7)
                : "v"(srcb),        "v"(srcb + 512),  "v"(srcb + 1024), "v"(srcb + 1536),
                  "v"(srcb + 2048), "v"(srcb + 2560), "v"(srcb + 3072), "v"(srcb + 3584)
                : "memory");
            const int d = tid * 4;
            *(float4*)&lds[O_U + 0 * 1024 + d] = r0;
            *(float4*)&lds[O_U + 1 * 1024 + d] = r1;
            *(float4*)&lds[O_U + 2 * 1024 + d] = r2;
            *(float4*)&lds[O_U + 3 * 1024 + d] = r3;
            *(float4*)&lds[O_U + 4 * 1024 + d] = r4;
            *(float4*)&lds[O_U + 5 * 1024 + d] = r5;
            *(float4*)&lds[O_U + 6 * 1024 + d] = r6;
            *(float4*)&lds[O_U + 7 * 1024 + d] = r7;
        }
        if (tid < 16 && s < T) {
            int b = tid >> 1, cm = tid & 1;
            lds[O_XS + tid] = xin[((bh * 8 + b) * (long)T + s) * 2 + cm];
        }
        __syncthreads();

        // ---- fused gate GEMMs: L2 (K=1024) + L1 (K=512), shared h loads ----
        float a1[4][8], a2[4][8];
        #pragma unroll
        for (int r = 0; r < 4; ++r)
            #pragma unroll
            for (int b = 0; b < 8; ++b) { a1[r][b] = 0.0f; a2[r][b] = 0.0f; }
        {
            const float* W2b = &lds[O_W2 + wv * 4096];
            const float* W1b = &lds[O_W1 + wv * 2048];
            #pragma unroll
            for (int c = 0; c < 4; ++c) {
                const int k = ks * 4 + c * 256;
                float4 u0 = *(const float4*)&W2b[k];
                float4 u1 = *(const float4*)&W2b[1024 + k];
                float4 u2 = *(const float4*)&W2b[2048 + k];
                float4 u3 = *(const float4*)&W2b[3072 + k];
                float4 w0, w1, w2, w3;
                if (c < 2) {
                    w0 = *(const float4*)&W1b[k];
                    w1 = *(const float4*)&W1b[512 + k];
                    w2 = *(const float4*)&W1b[1024 + k];
                    w3 = *(const float4*)&W1b[1536 + k];
                }
                #pragma unroll
                for (int b = 0; b < 8; ++b) {
                    float4 h = *(const float4*)&lds[O_U + b * 1024 + k];
                    a2[0][b] = fmaf(u0.x,h.x,fmaf(u0.y,h.y,fmaf(u0.z,h.z,fmaf(u0.w,h.w,a2[0][b]))));
                    a2[1][b] = fmaf(u1.x,h.x,fmaf(u1.y,h.y,fmaf(u1.z,h.z,fmaf(u1.w,h.w,a2[1][b]))));
                    a2[2][b] = fmaf(u2.x,h.x,fmaf(u2.y,h.y,fmaf(u2.z,h.z,fmaf(u2.w,h.w,a2[2][b]))));
                    a2[3][b] = fmaf(u3.x,h.x,fmaf(u3.y,h.y,fmaf(u3.z,h.z,fmaf(u3.w,h.w,a2[3][b]))));
                    if (c < 2) {
                        a1[0][b] = fmaf(w0.x,h.x,fmaf(w0.y,h.y,fmaf(w0.z,h.z,fmaf(w0.w,h.w,a1[0][b]))));
                        a1[1][b] = fmaf(w1.x,h.x,fmaf(w1.y,h.y,fmaf(w1.z,h.z,fmaf(w1.w,h.w,a1[1][b]))));
                        a1[2][b] = fmaf(w2.x,h.x,fmaf(w2.y,h.y,fmaf(w2.z,h.z,fmaf(w2.w,h.w,a1[2][b]))));
                        a1[3][b] = fmaf(w3.x,h.x,fmaf(w3.y,h.y,fmaf(w3.z,h.z,fmaf(w3.w,h.w,a1[3][b]))));
                    }
                }
            }
        }
        __syncthreads();                // staged-h reads done; U becomes red[]

        // ---- reduce L1 (stride 68: 16B-aligned float4 reads, 0-conflict proven) ----
        #pragma unroll
        for (int r = 0; r < 4; ++r)
            #pragma unroll
            for (int b = 0; b < 8; ++b)
                lds[O_U + ((wv * 4 + r) * 8 + b) * 68 + ks] = a1[r][b];
        __syncthreads();
        {
            int o = tid >> 1, hf = tid & 1;
            const float* rr = &lds[O_U + o * 68 + hf * 32];
            float sum = 0.0f;
            #pragma unroll
            for (int c = 0; c < 8; ++c) { float4 v = *(const float4*)&rr[c * 4]; sum += v.x + v.y + v.z + v.w; }
            sum += __shfl_xor(sum, 1);
            if (hf == 0) {
                int r = o >> 3, b = o & 7;
                lds[O_G1 + o] = sum + lds[O_B1 + r]
                              + lds[O_WX + r * 2]     * lds[O_XS + b * 2]
                              + lds[O_WX + r * 2 + 1] * lds[O_XS + b * 2 + 1];
            }
        }
        __syncthreads();

        // ---- EARLY L1 activations + publish h1 (ack overlaps L2 reduce) ----
        if (tid < 32 && s < T) {
            int jj = tid >> 3, b = tid & 7;
            float gi = sigm(lds[O_G1 + (0 * 4 + jj) * 8 + b]);
            float gf = sigm(lds[O_G1 + (1 * 4 + jj) * 8 + b]);
            float gg = tanh_fast(lds[O_G1 + (2 * 4 + jj) * 8 + b]);
            float go = sigm(lds[O_G1 + (3 * 4 + jj) * 8 + b]);
            float c  = gf * lds[O_C1 + tid] + gi * gg;
            lds[O_C1 + tid] = c;
            __hip_atomic_store(&h1g[p * 8192 + (bh * 8 + b) * 512 + j0 + jj],
                               go * tanh_fast(c), __ATOMIC_RELAXED, AGT);
        }

        // ---- reduce L2 ----
        #pragma unroll
        for (int r = 0; r < 4; ++r)
            #pragma unroll
            for (int b = 0; b < 8; ++b)
                lds[O_U + ((wv * 4 + r) * 8 + b) * 68 + ks] = a2[r][b];
        __syncthreads();
        {
            int o = tid >> 1, hf = tid & 1;
            const float* rr = &lds[O_U + o * 68 + hf * 32];
            float sum = 0.0f;
            #pragma unroll
            for (int c = 0; c < 8; ++c) { float4 v = *(const float4*)&rr[c * 4]; sum += v.x + v.y + v.z + v.w; }
            sum += __shfl_xor(sum, 1);
            if (hf == 0) lds[O_G2 + o] = sum + lds[O_B2 + (o >> 3)];
        }
        __syncthreads();

        // ---- L2 activations + publish h2 ----
        if (tid >= 32 && tid < 64 && s >= 1) {
            int t2 = tid - 32, jj = t2 >> 3, b = t2 & 7;
            float gi = sigm(lds[O_G2 + (0 * 4 + jj) * 8 + b]);
            float gf = sigm(lds[O_G2 + (1 * 4 + jj) * 8 + b]);
            float gg = tanh_fast(lds[O_G2 + (2 * 4 + jj) * 8 + b]);
            float go = sigm(lds[O_G2 + (3 * 4 + jj) * 8 + b]);
            float c  = gf * lds[O_C2 + t2] + gi * gg;
            lds[O_C2 + t2] = c;
            float h = go * tanh_fast(c);
            __hip_atomic_store(&h2g[p * 8192 + (bh * 8 + b) * 512 + j0 + jj],
                               h, __ATOMIC_RELAXED, AGT);
            lds[O_HN + t2] = lds[O_WO + jj] * h;
        }
        __syncthreads();   // HN written by lanes 32-63, read by lanes 0-7
        if (tid < 8 && s >= 1) {
            float pr = lds[O_HN + tid] + lds[O_HN + 8 + tid]
                     + lds[O_HN + 16 + tid] + lds[O_HN + 24 + tid];
            __hip_atomic_store(&outred[p * 2048 + (bh * 8 + tid) * 128 + jg],
                               pr, __ATOMIC_RELAXED, AGT);
        }

        gbar(flags, wg, tid, ++ph);     // half-barrier, one per superstep
    }

    // tail: y_{T-1} partials (outred parity T&1, written at s=T, covered by last bar)
    if (tid == 0) {
        const unsigned long long* row64 =
            (const unsigned long long*)(outred + (T & 1) * 2048 + bd * 128 + jh * 8);
        U64F2 v0; v0.u = __hip_atomic_load(&row64[0], __ATOMIC_RELAXED, AGT);
        U64F2 v1; v1.u = __hip_atomic_load(&row64[1], __ATOMIC_RELAXED, AGT);
        U64F2 v2; v2.u = __hip_atomic_load(&row64[2], __ATOMIC_RELAXED, AGT);
        U64F2 v3; v3.u = __hip_atomic_load(&row64[3], __ATOMIC_RELAXED, AGT);
        float sum = (v0.f[0] + v0.f[1]) + (v1.f[0] + v1.f[1])
                  + (v2.f[0] + v2.f[1]) + (v3.f[0] + v3.f[1]);
        atomicAdd(&out[bd * T + (T - 1)], sum);
    }
}

extern "C" void kernel_launch(void* const* d_in, const int* in_sizes, int n_in,
                              void* d_out, int out_size, void* d_ws, size_t ws_size,
                              hipStream_t stream) {
    const float* xin  = (const float*)d_in[0];
    const float* Wih1 = (const float*)d_in[1];
    const float* Whh1 = (const float*)d_in[2];
    const float* bih1 = (const float*)d_in[3];
    const float* bhh1 = (const float*)d_in[4];
    const float* Wih2 = (const float*)d_in[5];
    const float* Whh2 = (const float*)d_in[6];
    const float* bih2 = (const float*)d_in[7];
    const float* bhh2 = (const float*)d_in[8];
    const float* Wout = (const float*)d_in[9];
    const float* bout = (const float*)d_in[10];
    float* outp = (float*)d_out;
    int T = in_sizes[0] / 32;           // input is [16][T][2]

    unsigned* flags = (unsigned*)d_ws;                  // [half0 x128 | half1 x128]
    float* h1g    = (float*)d_ws + 4096;                // [2][16][512] (zero-init)
    float* h2g    = h1g + 16384;                        // [2][16][512] (zero-init)
    float* outredp= h2g + 16384;                        // [2][16][128]

    hipLaunchKernelGGL(ws_init_kernel, dim3(64), dim3(256), 0, stream,
                       flags, h1g, h2g, outp, bout, out_size);

    // PLAIN launch (R11/R12-validated): cooperative launch silently flakes.
    // Co-residency is structural: 134KB LDS -> 1 block/CU, grid == 256 == CUs.
    hipLaunchKernelGGL(lstm_kernel, dim3(NWG), dim3(NTHR), 0, stream,
                       xin, Wih1, Whh1, bih1, bhh1, Wih2, Whh2, bih2, bhh2,
                       Wout, bout, outp, flags, h1g, h2g, outredp, T);
}

// Round 15
// 53985.388 us; speedup vs baseline: 1.6571x; 1.0367x over previous
//
#include <hip/hip_runtime.h>
#include <math.h>

#define NWG  256
#define NTHR 256
#define AGT __HIP_MEMORY_SCOPE_AGENT

// LDS float offsets
#define O_W2  0        // [16][1024]  W2 = [W_ih2 | W_hh2] rows for this j-group
#define O_W1  16384    // [16][512]   W_hh1 rows
#define O_U   24576    // union: hstage [8][1024] / red [128][68] (8704 floats)
#define O_WX  33280    // [16][2]     W_ih1 (K=2)
#define O_B1  33312    // [16]
#define O_B2  33328    // [16]
#define O_WO  33344    // [4]
#define O_XS  33348    // [8][2]
#define O_G1  33364    // [128] layer-1 gates (pre-activated)
#define O_G2  33492    // [128] layer-2 gates (pre-activated)
#define O_C1  33620    // [32]
#define O_C2  33652    // [32]
#define LDS_FLOATS 33684

union U64F2 { unsigned long long u; float f[2]; };

__global__ void ws_init_kernel(unsigned* flags, float* h1g, float* h2g,
                               float* out, const float* bout, int n_out) {
    int i = blockIdx.x * blockDim.x + threadIdx.x;
    int n = gridDim.x * blockDim.x;
    float bo = bout[0];
    for (int j = i; j < NWG; j += n) flags[j] = 0u;
    for (int j = i; j < 16384; j += n) { h1g[j] = 0.0f; h2g[j] = 0.0f; }
    for (int j = i; j < n_out; j += n) out[j] = bo;   // duty atomicAdds onto b_out
}

__device__ __forceinline__ float sigm(float x) { return 1.0f / (1.0f + __expf(-x)); }
__device__ __forceinline__ float tanh_fast(float x) { return 2.0f / (1.0f + __expf(-2.0f * x)) - 1.0f; }

// Half-split fence-free barrier (R13/R14-validated): each WG syncs only its
// own 128 same-half WGs. flags[0..127] = half 0, flags[128..255] = half 1.
__device__ __forceinline__ void gbar(unsigned* flags, int wg, int tid, unsigned ph) {
    __syncthreads();
    asm volatile("s_waitcnt vmcnt(0)" ::: "memory");     // drain this wave's IC ops
    const int half = wg & 1;
    if (tid == 0)
        __hip_atomic_store(&flags[(half << 7) + (wg >> 1)], ph, __ATOMIC_RELAXED, AGT);
    if (tid < 32) {
        const unsigned long long* f64 = (const unsigned long long*)flags + (half << 6);
        bool done;
        do {
            unsigned long long v0 = __hip_atomic_load(&f64[2 * tid],     __ATOMIC_RELAXED, AGT);
            unsigned long long v1 = __hip_atomic_load(&f64[2 * tid + 1], __ATOMIC_RELAXED, AGT);
            done = ((unsigned)v0 >= ph) && ((unsigned)(v0 >> 32) >= ph) &&
                   ((unsigned)v1 >= ph) && ((unsigned)(v1 >> 32) >= ph);
            if (!__all(done)) __builtin_amdgcn_s_sleep(1);
        } while (!__all(done));
    }
    __syncthreads();
}

__global__ __launch_bounds__(NTHR, 1) void lstm_kernel(
    const float* __restrict__ xin,  const float* __restrict__ Wih1,
    const float* __restrict__ Whh1, const float* __restrict__ bih1,
    const float* __restrict__ bhh1, const float* __restrict__ Wih2,
    const float* __restrict__ Whh2, const float* __restrict__ bih2,
    const float* __restrict__ bhh2, const float* __restrict__ Wout,
    const float* __restrict__ bout, float* __restrict__ out,
    unsigned* __restrict__ flags, float* __restrict__ h1g,
    float* __restrict__ h2g, float* __restrict__ outred, int T)
{
    __shared__ float lds[LDS_FLOATS];
    const int tid = threadIdx.x;
    const int wg  = blockIdx.x;
    const int bh  = wg & 1;         // batch half: batches bh*8 .. bh*8+7
    const int jg  = wg >> 1;        // hidden-j group
    const int j0  = jg * 4;
    const int bd  = bh * 8 + (jg & 7);  // duty batch (same half as this WG)
    const int jh  = jg >> 3;            // duty jg-octet

    // ---- one-time: load weight slice into LDS ----
    for (int idx = tid; idx < 2048; idx += NTHR) {          // W1 = W_hh1 rows
        int r = idx >> 7, c4 = idx & 127;
        int grow = (r >> 2) * 512 + j0 + (r & 3);           // local row q*4+jj -> global q*512+j
        *(float4*)&lds[O_W1 + r * 512 + c4 * 4] = *(const float4*)&Whh1[grow * 512 + c4 * 4];
    }
    for (int idx = tid; idx < 4096; idx += NTHR) {          // W2 = [W_ih2 | W_hh2]
        int r = idx >> 8, c4 = idx & 255;
        int grow = (r >> 2) * 512 + j0 + (r & 3);
        int k = c4 * 4;
        const float* src = (k < 512) ? &Wih2[grow * 512 + k] : &Whh2[grow * 512 + (k - 512)];
        *(float4*)&lds[O_W2 + r * 1024 + k] = *(const float4*)src;
    }
    if (tid < 32) {
        int r = tid >> 1, grow = (r >> 2) * 512 + j0 + (r & 3);
        lds[O_WX + tid] = Wih1[grow * 2 + (tid & 1)];
    }
    if (tid < 16) {
        int grow = (tid >> 2) * 512 + j0 + (tid & 3);
        lds[O_B1 + tid] = bih1[grow] + bhh1[grow];
        lds[O_B2 + tid] = bih2[grow] + bhh2[grow];
    }
    if (tid < 4) lds[O_WO + tid] = Wout[j0 + tid];
    if (tid < 32) { lds[O_C1 + tid] = 0.0f; lds[O_C2 + tid] = 0.0f; }
    __syncthreads();

    const int wv = tid >> 6;        // wave -> 4 gate rows; also == gate index in reduce
    const int ks = tid & 63;        // K-split lane
    unsigned ph = 0;

    // xin register prefetch (one superstep ahead)
    float xreg = 0.0f;
    if (tid < 16 && T > 0) {
        int b = tid >> 1, cm = tid & 1;
        xreg = xin[((bh * 8 + b) * (long)T + 0) * 2 + cm];
    }

    // superstep s: compute h1_s (layer1, s<T) and h2_{s-1} (layer2, s>=1).
    // ONE half-barrier per superstep. h1g/h2g pre-zeroed.
    for (int s = 0; s <= T; ++s) {
        const int p = s & 1, pq = p ^ 1;

        // ---- out duty, spread over all WGs (atomicAdd onto b_out-prefilled out) ----
        if (s >= 2 && tid == 0) {
            const unsigned long long* row64 =
                (const unsigned long long*)(outred + pq * 2048 + bd * 128 + jh * 8);
            U64F2 v0; v0.u = __hip_atomic_load(&row64[0], __ATOMIC_RELAXED, AGT);
            U64F2 v1; v1.u = __hip_atomic_load(&row64[1], __ATOMIC_RELAXED, AGT);
            U64F2 v2; v2.u = __hip_atomic_load(&row64[2], __ATOMIC_RELAXED, AGT);
            U64F2 v3; v3.u = __hip_atomic_load(&row64[3], __ATOMIC_RELAXED, AGT);
            float sum = (v0.f[0] + v0.f[1]) + (v1.f[0] + v1.f[1])
                      + (v2.f[0] + v2.f[1]) + (v3.f[0] + v3.f[1]);
            atomicAdd(&out[bd * T + (s - 2)], sum);
        }

        // ---- XS from prefetched register; issue next-step prefetch ----
        if (tid < 16) {
            if (s < T) lds[O_XS + tid] = xreg;
            if (s + 1 < T) {
                int b = tid >> 1, cm = tid & 1;
                xreg = xin[((bh * 8 + b) * (long)T + (s + 1)) * 2 + cm];
            }
        }

        // ---- stage U = [h1_{s-1} | h2_{s-2}] via COALESCED coherent loads ----
        // global_load_dwordx4 sc0 sc1: reads through to the coherence point,
        // 16B-wide and lane-coalesced (R14-validated, 8x fewer IC transactions).
        {
            const float* srcb = (tid < 128)
                ? (h1g + pq * 8192 + (bh * 8) * 512 + tid * 4)
                : (h2g + pq * 8192 + (bh * 8) * 512 + (tid - 128) * 4);
            float4 r0, r1, r2, r3, r4, r5, r6, r7;
            asm volatile(
                "global_load_dwordx4 %0, %8, off sc0 sc1\n\t"
                "global_load_dwordx4 %1, %9, off sc0 sc1\n\t"
                "global_load_dwordx4 %2, %10, off sc0 sc1\n\t"
                "global_load_dwordx4 %3, %11, off sc0 sc1\n\t"
                "global_load_dwordx4 %4, %12, off sc0 sc1\n\t"
                "global_load_dwordx4 %5, %13, off sc0 sc1\n\t"
                "global_load_dwordx4 %6, %14, off sc0 sc1\n\t"
                "global_load_dwordx4 %7, %15, off sc0 sc1\n\t"
                "s_waitcnt vmcnt(0)"
                : "=&v"(r0), "=&v"(r1), "=&v"(r2), "=&v"(r3),
                  "=&v"(r4), "=&v"(r5), "=&v"(r6), "=&v"(r7)
                : "v"(srcb),        "v"(srcb + 512),  "v"(srcb + 1024), "v"(srcb + 1536),
                  "v"(srcb + 2048), "v"(srcb + 2560), "v"(srcb + 3072), "v"(srcb + 3584)
                : "memory");
            const int d = tid * 4;
            *(float4*)&lds[O_U + 0 * 1024 + d] = r0;
            *(float4*)&lds[O_U + 1 * 1024 + d] = r1;
            *(float4*)&lds[O_U + 2 * 1024 + d] = r2;
            *(float4*)&lds[O_U + 3 * 1024 + d] = r3;
            *(float4*)&lds[O_U + 4 * 1024 + d] = r4;
            *(float4*)&lds[O_U + 5 * 1024 + d] = r5;
            *(float4*)&lds[O_U + 6 * 1024 + d] = r6;
            *(float4*)&lds[O_U + 7 * 1024 + d] = r7;
        }
        __syncthreads();

        // ---- fused gate GEMMs: L2 (K=1024) + L1 (K=512), shared h loads ----
        float a1[4][8], a2[4][8];
        #pragma unroll
        for (int r = 0; r < 4; ++r)
            #pragma unroll
            for (int b = 0; b < 8; ++b) { a1[r][b] = 0.0f; a2[r][b] = 0.0f; }
        {
            const float* W2b = &lds[O_W2 + wv * 4096];
            const float* W1b = &lds[O_W1 + wv * 2048];
            #pragma unroll
            for (int c = 0; c < 4; ++c) {
                const int k = ks * 4 + c * 256;
                float4 u0 = *(const float4*)&W2b[k];
                float4 u1 = *(const float4*)&W2b[1024 + k];
                float4 u2 = *(const float4*)&W2b[2048 + k];
                float4 u3 = *(const float4*)&W2b[3072 + k];
                float4 w0, w1, w2, w3;
                if (c < 2) {
                    w0 = *(const float4*)&W1b[k];
                    w1 = *(const float4*)&W1b[512 + k];
                    w2 = *(const float4*)&W1b[1024 + k];
                    w3 = *(const float4*)&W1b[1536 + k];
                }
                #pragma unroll
                for (int b = 0; b < 8; ++b) {
                    float4 h = *(const float4*)&lds[O_U + b * 1024 + k];
                    a2[0][b] = fmaf(u0.x,h.x,fmaf(u0.y,h.y,fmaf(u0.z,h.z,fmaf(u0.w,h.w,a2[0][b]))));
                    a2[1][b] = fmaf(u1.x,h.x,fmaf(u1.y,h.y,fmaf(u1.z,h.z,fmaf(u1.w,h.w,a2[1][b]))));
                    a2[2][b] = fmaf(u2.x,h.x,fmaf(u2.y,h.y,fmaf(u2.z,h.z,fmaf(u2.w,h.w,a2[2][b]))));
                    a2[3][b] = fmaf(u3.x,h.x,fmaf(u3.y,h.y,fmaf(u3.z,h.z,fmaf(u3.w,h.w,a2[3][b]))));
                    if (c < 2) {
                        a1[0][b] = fmaf(w0.x,h.x,fmaf(w0.y,h.y,fmaf(w0.z,h.z,fmaf(w0.w,h.w,a1[0][b]))));
                        a1[1][b] = fmaf(w1.x,h.x,fmaf(w1.y,h.y,fmaf(w1.z,h.z,fmaf(w1.w,h.w,a1[1][b]))));
                        a1[2][b] = fmaf(w2.x,h.x,fmaf(w2.y,h.y,fmaf(w2.z,h.z,fmaf(w2.w,h.w,a1[2][b]))));
                        a1[3][b] = fmaf(w3.x,h.x,fmaf(w3.y,h.y,fmaf(w3.z,h.z,fmaf(w3.w,h.w,a1[3][b]))));
                    }
                }
            }
        }
        __syncthreads();                // staged-h reads done; U becomes red[]

        // ---- reduce L1 (stride 68, 0-conflict) + PRE-ACTIVATION (wave-uniform) ----
        #pragma unroll
        for (int r = 0; r < 4; ++r)
            #pragma unroll
            for (int b = 0; b < 8; ++b)
                lds[O_U + ((wv * 4 + r) * 8 + b) * 68 + ks] = a1[r][b];
        __syncthreads();
        {
            int o = tid >> 1, hf = tid & 1;
            const float* rr = &lds[O_U + o * 68 + hf * 32];
            float sum = 0.0f;
            #pragma unroll
            for (int c = 0; c < 8; ++c) { float4 v = *(const float4*)&rr[c * 4]; sum += v.x + v.y + v.z + v.w; }
            sum += __shfl_xor(sum, 1);
            if (hf == 0) {
                int r = o >> 3, b = o & 7;      // r = gate*4+jj; gate = o>>5 == wv
                float g = sum + lds[O_B1 + r]
                        + lds[O_WX + r * 2]     * lds[O_XS + b * 2]
                        + lds[O_WX + r * 2 + 1] * lds[O_XS + b * 2 + 1];
                lds[O_G1 + o] = (wv == 2) ? tanh_fast(g) : sigm(g);   // gate 2 = g-gate
            }
        }
        __syncthreads();

        // ---- EARLY L1 cell update + publish h1 (ack overlaps L2 reduce) ----
        if (tid < 32 && s < T) {
            int jj = tid >> 3, b = tid & 7;
            float gi = lds[O_G1 + (0 * 4 + jj) * 8 + b];
            float gf = lds[O_G1 + (1 * 4 + jj) * 8 + b];
            float gg = lds[O_G1 + (2 * 4 + jj) * 8 + b];
            float go = lds[O_G1 + (3 * 4 + jj) * 8 + b];
            float c  = gf * lds[O_C1 + tid] + gi * gg;
            lds[O_C1 + tid] = c;
            __hip_atomic_store(&h1g[p * 8192 + (bh * 8 + b) * 512 + j0 + jj],
                               go * tanh_fast(c), __ATOMIC_RELAXED, AGT);
        }

        // ---- reduce L2 + pre-activation ----
        #pragma unroll
        for (int r = 0; r < 4; ++r)
            #pragma unroll
            for (int b = 0; b < 8; ++b)
                lds[O_U + ((wv * 4 + r) * 8 + b) * 68 + ks] = a2[r][b];
        __syncthreads();
        {
            int o = tid >> 1, hf = tid & 1;
            const float* rr = &lds[O_U + o * 68 + hf * 32];
            float sum = 0.0f;
            #pragma unroll
            for (int c = 0; c < 8; ++c) { float4 v = *(const float4*)&rr[c * 4]; sum += v.x + v.y + v.z + v.w; }
            sum += __shfl_xor(sum, 1);
            if (hf == 0) {
                float g = sum + lds[O_B2 + (o >> 3)];
                lds[O_G2 + o] = (wv == 2) ? tanh_fast(g) : sigm(g);
            }
        }
        __syncthreads();

        // ---- L2 cell update + publish h2 + in-register outred fold ----
        if (tid >= 32 && tid < 64 && s >= 1) {
            int t2 = tid - 32, jj = t2 >> 3, b = t2 & 7;
            float gi = lds[O_G2 + (0 * 4 + jj) * 8 + b];
            float gf = lds[O_G2 + (1 * 4 + jj) * 8 + b];
            float gg = lds[O_G2 + (2 * 4 + jj) * 8 + b];
            float go = lds[O_G2 + (3 * 4 + jj) * 8 + b];
            float c  = gf * lds[O_C2 + t2] + gi * gg;
            lds[O_C2 + t2] = c;
            float h = go * tanh_fast(c);
            __hip_atomic_store(&h2g[p * 8192 + (bh * 8 + b) * 512 + j0 + jj],
                               h, __ATOMIC_RELAXED, AGT);
            // fold WO[jj]*h over jj (lane bits 3-4) -> per-b sums; jj==0 lanes store
            float hn = lds[O_WO + jj] * h;
            hn += __shfl_xor(hn, 8);
            hn += __shfl_xor(hn, 16);
            if (jj == 0)
                __hip_atomic_store(&outred[p * 2048 + (bh * 8 + b) * 128 + jg],
                                   hn, __ATOMIC_RELAXED, AGT);
        }

        gbar(flags, wg, tid, ++ph);     // half-barrier, one per superstep
    }

    // tail: y_{T-1} partials (outred parity T&1, written at s=T, covered by last bar)
    if (tid == 0) {
        const unsigned long long* row64 =
            (const unsigned long long*)(outred + (T & 1) * 2048 + bd * 128 + jh * 8);
        U64F2 v0; v0.u = __hip_atomic_load(&row64[0], __ATOMIC_RELAXED, AGT);
        U64F2 v1; v1.u = __hip_atomic_load(&row64[1], __ATOMIC_RELAXED, AGT);
        U64F2 v2; v2.u = __hip_atomic_load(&row64[2], __ATOMIC_RELAXED, AGT);
        U64F2 v3; v3.u = __hip_atomic_load(&row64[3], __ATOMIC_RELAXED, AGT);
        float sum = (v0.f[0] + v0.f[1]) + (v1.f[0] + v1.f[1])
                  + (v2.f[0] + v2.f[1]) + (v3.f[0] + v3.f[1]);
        atomicAdd(&out[bd * T + (T - 1)], sum);
    }
}

extern "C" void kernel_launch(void* const* d_in, const int* in_sizes, int n_in,
                              void* d_out, int out_size, void* d_ws, size_t ws_size,
                              hipStream_t stream) {
    const float* xin  = (const float*)d_in[0];
    const float* Wih1 = (const float*)d_in[1];
    const float* Whh1 = (const float*)d_in[2];
    const float* bih1 = (const float*)d_in[3];
    const float* bhh1 = (const float*)d_in[4];
    const float* Wih2 = (const float*)d_in[5];
    const float* Whh2 = (const float*)d_in[6];
    const float* bih2 = (const float*)d_in[7];
    const float* bhh2 = (const float*)d_in[8];
    const float* Wout = (const float*)d_in[9];
    const float* bout = (const float*)d_in[10];
    float* outp = (float*)d_out;
    int T = in_sizes[0] / 32;           // input is [16][T][2]

    unsigned* flags = (unsigned*)d_ws;                  // [half0 x128 | half1 x128]
    float* h1g    = (float*)d_ws + 4096;                // [2][16][512] (zero-init)
    float* h2g    = h1g + 16384;                        // [2][16][512] (zero-init)
    float* outredp= h2g + 16384;                        // [2][16][128]

    hipLaunchKernelGGL(ws_init_kernel, dim3(64), dim3(256), 0, stream,
                       flags, h1g, h2g, outp, bout, out_size);

    // PLAIN launch (R11/R12-validated): cooperative launch silently flakes.
    // Co-residency is structural: 134KB LDS -> 1 block/CU, grid == 256 == CUs.
    hipLaunchKernelGGL(lstm_kernel, dim3(NWG), dim3(NTHR), 0, stream,
                       xin, Wih1, Whh1, bih1, bhh1, Wih2, Whh2, bih2, bhh2,
                       Wout, bout, outp, flags, h1g, h2g, outredp, T);
}

// Round 16
// 53762.469 us; speedup vs baseline: 1.6640x; 1.0041x over previous
//
#include <hip/hip_runtime.h>
#include <math.h>

#define NWG  256
#define NTHR 256
#define AGT __HIP_MEMORY_SCOPE_AGENT

// LDS float offsets
#define O_W2  0        // [16][1024]  W2 = [W_ih2 | W_hh2] rows for this j-group
#define O_W1  16384    // [16][512]   W_hh1 rows
#define O_U   24576    // union: hstage [8][1024] / red [128][68] (8704 floats)
#define O_WX  33280    // [16][2]     W_ih1 (K=2)
#define O_B1  33312    // [16]
#define O_B2  33328    // [16]
#define O_WO  33344    // [4]
#define O_XS  33348    // [8][2]
#define O_G1  33364    // [128] layer-1 gates (pre-activated)
#define O_G2  33492    // [128] layer-2 gates (pre-activated)
#define O_C1  33620    // [32]
#define O_C2  33652    // [32]
#define LDS_FLOATS 33684

union U64F2 { unsigned long long u; float f[2]; };

__global__ void ws_init_kernel(unsigned* flags, float* h1g, float* h2g,
                               float* out, const float* bout, int n_out) {
    int i = blockIdx.x * blockDim.x + threadIdx.x;
    int n = gridDim.x * blockDim.x;
    float bo = bout[0];
    for (int j = i; j < 512; j += n) flags[j] = 0u;    // flagsB[256] + flagsA[256]
    for (int j = i; j < 16384; j += n) { h1g[j] = 0.0f; h2g[j] = 0.0f; }
    for (int j = i; j < n_out; j += n) out[j] = bo;    // duty atomicAdds onto b_out
}

__device__ __forceinline__ float sigm(float x) { return 1.0f / (1.0f + __expf(-x)); }
__device__ __forceinline__ float tanh_fast(float x) { return 2.0f / (1.0f + __expf(-2.0f * x)) - 1.0f; }

// Half-split fence-free barrier (R13-R15 validated).
__device__ __forceinline__ void gbar(unsigned* flags, int wg, int tid, unsigned ph) {
    __syncthreads();
    asm volatile("s_waitcnt vmcnt(0)" ::: "memory");     // drain this wave's IC ops
    const int half = wg & 1;
    if (tid == 0)
        __hip_atomic_store(&flags[(half << 7) + (wg >> 1)], ph, __ATOMIC_RELAXED, AGT);
    if (tid < 32) {
        const unsigned long long* f64 = (const unsigned long long*)flags + (half << 6);
        bool done;
        do {
            unsigned long long v0 = __hip_atomic_load(&f64[2 * tid],     __ATOMIC_RELAXED, AGT);
            unsigned long long v1 = __hip_atomic_load(&f64[2 * tid + 1], __ATOMIC_RELAXED, AGT);
            done = ((unsigned)v0 >= ph) && ((unsigned)(v0 >> 32) >= ph) &&
                   ((unsigned)v1 >= ph) && ((unsigned)(v1 >> 32) >= ph);
            if (!__all(done)) __builtin_amdgcn_s_sleep(1);
        } while (!__all(done));
    }
    __syncthreads();
}

// 8x coalesced coherent float4 loads (R14-validated sc0 sc1 = read-through to IC)
#define STAGE8(srcb, r0,r1,r2,r3,r4,r5,r6,r7)                            \
    asm volatile(                                                         \
        "global_load_dwordx4 %0, %8, off sc0 sc1\n\t"                     \
        "global_load_dwordx4 %1, %9, off sc0 sc1\n\t"                     \
        "global_load_dwordx4 %2, %10, off sc0 sc1\n\t"                    \
        "global_load_dwordx4 %3, %11, off sc0 sc1\n\t"                    \
        "global_load_dwordx4 %4, %12, off sc0 sc1\n\t"                    \
        "global_load_dwordx4 %5, %13, off sc0 sc1\n\t"                    \
        "global_load_dwordx4 %6, %14, off sc0 sc1\n\t"                    \
        "global_load_dwordx4 %7, %15, off sc0 sc1\n\t"                    \
        "s_waitcnt vmcnt(0)"                                              \
        : "=&v"(r0), "=&v"(r1), "=&v"(r2), "=&v"(r3),                     \
          "=&v"(r4), "=&v"(r5), "=&v"(r6), "=&v"(r7)                      \
        : "v"(srcb),        "v"(srcb + 512),  "v"(srcb + 1024),           \
          "v"(srcb + 1536), "v"(srcb + 2048), "v"(srcb + 2560),           \
          "v"(srcb + 3072), "v"(srcb + 3584)                              \
        : "memory")

__global__ __launch_bounds__(NTHR, 1) void lstm_kernel(
    const float* __restrict__ xin,  const float* __restrict__ Wih1,
    const float* __restrict__ Whh1, const float* __restrict__ bih1,
    const float* __restrict__ bhh1, const float* __restrict__ Wih2,
    const float* __restrict__ Whh2, const float* __restrict__ bih2,
    const float* __restrict__ bhh2, const float* __restrict__ Wout,
    const float* __restrict__ bout, float* __restrict__ out,
    unsigned* __restrict__ flags, float* __restrict__ h1g,
    float* __restrict__ h2g, float* __restrict__ outred, int T)
{
    __shared__ float lds[LDS_FLOATS];
    const int tid = threadIdx.x;
    const int wg  = blockIdx.x;
    const int bh  = wg & 1;         // batch half: batches bh*8 .. bh*8+7
    const int jg  = wg >> 1;        // hidden-j group
    const int j0  = jg * 4;
    const int bd  = bh * 8 + (jg & 7);  // duty batch (same half as this WG)
    const int jh  = jg >> 3;            // duty jg-octet
    unsigned* flagsA = flags + 256;     // early h1-ready flags (same half layout)

    // ---- one-time: load weight slice into LDS ----
    for (int idx = tid; idx < 2048; idx += NTHR) {          // W1 = W_hh1 rows
        int r = idx >> 7, c4 = idx & 127;
        int grow = (r >> 2) * 512 + j0 + (r & 3);           // local row q*4+jj -> global q*512+j
        *(float4*)&lds[O_W1 + r * 512 + c4 * 4] = *(const float4*)&Whh1[grow * 512 + c4 * 4];
    }
    for (int idx = tid; idx < 4096; idx += NTHR) {          // W2 = [W_ih2 | W_hh2]
        int r = idx >> 8, c4 = idx & 255;
        int grow = (r >> 2) * 512 + j0 + (r & 3);
        int k = c4 * 4;
        const float* src = (k < 512) ? &Wih2[grow * 512 + k] : &Whh2[grow * 512 + (k - 512)];
        *(float4*)&lds[O_W2 + r * 1024 + k] = *(const float4*)src;
    }
    if (tid < 32) {
        int r = tid >> 1, grow = (r >> 2) * 512 + j0 + (r & 3);
        lds[O_WX + tid] = Wih1[grow * 2 + (tid & 1)];
    }
    if (tid < 16) {
        int grow = (tid >> 2) * 512 + j0 + (tid & 3);
        lds[O_B1 + tid] = bih1[grow] + bhh1[grow];
        lds[O_B2 + tid] = bih2[grow] + bhh2[grow];
    }
    if (tid < 4) lds[O_WO + tid] = Wout[j0 + tid];
    if (tid < 32) { lds[O_C1 + tid] = 0.0f; lds[O_C2 + tid] = 0.0f; }

    // ---- pre-loop: fill U-h1 with h1_{-1}=0 (from zeroed h1g parity 1) ----
    if (tid >= 128) {
        const float* srcb = h1g + 1 * 8192 + (bh * 8) * 512 + (tid - 128) * 4;
        float4 r0, r1, r2, r3, r4, r5, r6, r7;
        STAGE8(srcb, r0, r1, r2, r3, r4, r5, r6, r7);
        const int d = (tid - 128) * 4;
        *(float4*)&lds[O_U + 0 * 1024 + d] = r0;
        *(float4*)&lds[O_U + 1 * 1024 + d] = r1;
        *(float4*)&lds[O_U + 2 * 1024 + d] = r2;
        *(float4*)&lds[O_U + 3 * 1024 + d] = r3;
        *(float4*)&lds[O_U + 4 * 1024 + d] = r4;
        *(float4*)&lds[O_U + 5 * 1024 + d] = r5;
        *(float4*)&lds[O_U + 6 * 1024 + d] = r6;
        *(float4*)&lds[O_U + 7 * 1024 + d] = r7;
    }
    __syncthreads();

    const int wv = tid >> 6;        // wave -> 4 gate rows; also == gate index in reduce
    const int ks = tid & 63;        // K-split lane
    unsigned ph = 0;

    // xin register prefetch (one superstep ahead)
    float xreg = 0.0f;
    if (tid < 16 && T > 0) {
        int b = tid >> 1, cm = tid & 1;
        xreg = xin[((bh * 8 + b) * (long)T + 0) * 2 + cm];
    }

    // superstep s: compute h1_s (layer1, s<T) and h2_{s-1} (layer2, s>=1).
    // U-h1 (cols 0-511) was PRESTAGED before the barrier (waves 2-3, gated on
    // flagsA); only the h2 half (cols 512-1023) is staged post-barrier.
    for (int s = 0; s <= T; ++s) {
        const int p = s & 1, pq = p ^ 1;

        // ---- out duty, spread over all WGs (atomicAdd onto b_out-prefilled out) ----
        if (s >= 2 && tid == 0) {
            const unsigned long long* row64 =
                (const unsigned long long*)(outred + pq * 2048 + bd * 128 + jh * 8);
            U64F2 v0; v0.u = __hip_atomic_load(&row64[0], __ATOMIC_RELAXED, AGT);
            U64F2 v1; v1.u = __hip_atomic_load(&row64[1], __ATOMIC_RELAXED, AGT);
            U64F2 v2; v2.u = __hip_atomic_load(&row64[2], __ATOMIC_RELAXED, AGT);
            U64F2 v3; v3.u = __hip_atomic_load(&row64[3], __ATOMIC_RELAXED, AGT);
            float sum = (v0.f[0] + v0.f[1]) + (v1.f[0] + v1.f[1])
                      + (v2.f[0] + v2.f[1]) + (v3.f[0] + v3.f[1]);
            atomicAdd(&out[bd * T + (s - 2)], sum);
        }

        // ---- XS from prefetched register; issue next-step prefetch ----
        if (tid < 16) {
            if (s < T) lds[O_XS + tid] = xreg;
            if (s + 1 < T) {
                int b = tid >> 1, cm = tid & 1;
                xreg = xin[((bh * 8 + b) * (long)T + (s + 1)) * 2 + cm];
            }
        }

        // ---- post-barrier staging: h2_{s-2} half only (waves 0-1) ----
        if (tid < 128) {
            const float* srcb = h2g + pq * 8192 + (bh * 8) * 512 + tid * 4;
            float4 r0, r1, r2, r3, r4, r5, r6, r7;
            STAGE8(srcb, r0, r1, r2, r3, r4, r5, r6, r7);
            const int d = 512 + tid * 4;
            *(float4*)&lds[O_U + 0 * 1024 + d] = r0;
            *(float4*)&lds[O_U + 1 * 1024 + d] = r1;
            *(float4*)&lds[O_U + 2 * 1024 + d] = r2;
            *(float4*)&lds[O_U + 3 * 1024 + d] = r3;
            *(float4*)&lds[O_U + 4 * 1024 + d] = r4;
            *(float4*)&lds[O_U + 5 * 1024 + d] = r5;
            *(float4*)&lds[O_U + 6 * 1024 + d] = r6;
            *(float4*)&lds[O_U + 7 * 1024 + d] = r7;
        }
        __syncthreads();

        // ---- fused gate GEMMs: L2 (K=1024) + L1 (K=512), shared h loads ----
        float a1[4][8], a2[4][8];
        #pragma unroll
        for (int r = 0; r < 4; ++r)
            #pragma unroll
            for (int b = 0; b < 8; ++b) { a1[r][b] = 0.0f; a2[r][b] = 0.0f; }
        {
            const float* W2b = &lds[O_W2 + wv * 4096];
            const float* W1b = &lds[O_W1 + wv * 2048];
            #pragma unroll
            for (int c = 0; c < 4; ++c) {
                const int k = ks * 4 + c * 256;
                float4 u0 = *(const float4*)&W2b[k];
                float4 u1 = *(const float4*)&W2b[1024 + k];
                float4 u2 = *(const float4*)&W2b[2048 + k];
                float4 u3 = *(const float4*)&W2b[3072 + k];
                float4 w0, w1, w2, w3;
                if (c < 2) {
                    w0 = *(const float4*)&W1b[k];
                    w1 = *(const float4*)&W1b[512 + k];
                    w2 = *(const float4*)&W1b[1024 + k];
                    w3 = *(const float4*)&W1b[1536 + k];
                }
                #pragma unroll
                for (int b = 0; b < 8; ++b) {
                    float4 h = *(const float4*)&lds[O_U + b * 1024 + k];
                    a2[0][b] = fmaf(u0.x,h.x,fmaf(u0.y,h.y,fmaf(u0.z,h.z,fmaf(u0.w,h.w,a2[0][b]))));
                    a2[1][b] = fmaf(u1.x,h.x,fmaf(u1.y,h.y,fmaf(u1.z,h.z,fmaf(u1.w,h.w,a2[1][b]))));
                    a2[2][b] = fmaf(u2.x,h.x,fmaf(u2.y,h.y,fmaf(u2.z,h.z,fmaf(u2.w,h.w,a2[2][b]))));
                    a2[3][b] = fmaf(u3.x,h.x,fmaf(u3.y,h.y,fmaf(u3.z,h.z,fmaf(u3.w,h.w,a2[3][b]))));
                    if (c < 2) {
                        a1[0][b] = fmaf(w0.x,h.x,fmaf(w0.y,h.y,fmaf(w0.z,h.z,fmaf(w0.w,h.w,a1[0][b]))));
                        a1[1][b] = fmaf(w1.x,h.x,fmaf(w1.y,h.y,fmaf(w1.z,h.z,fmaf(w1.w,h.w,a1[1][b]))));
                        a1[2][b] = fmaf(w2.x,h.x,fmaf(w2.y,h.y,fmaf(w2.z,h.z,fmaf(w2.w,h.w,a1[2][b]))));
                        a1[3][b] = fmaf(w3.x,h.x,fmaf(w3.y,h.y,fmaf(w3.z,h.z,fmaf(w3.w,h.w,a1[3][b]))));
                    }
                }
            }
        }
        __syncthreads();                // staged-h reads done; U becomes red[]

        // ---- reduce L1 (stride 68, 0-conflict) + pre-activation (wave-uniform) ----
        #pragma unroll
        for (int r = 0; r < 4; ++r)
            #pragma unroll
            for (int b = 0; b < 8; ++b)
                lds[O_U + ((wv * 4 + r) * 8 + b) * 68 + ks] = a1[r][b];
        __syncthreads();
        {
            int o = tid >> 1, hf = tid & 1;
            const float* rr = &lds[O_U + o * 68 + hf * 32];
            float sum = 0.0f;
            #pragma unroll
            for (int c = 0; c < 8; ++c) { float4 v = *(const float4*)&rr[c * 4]; sum += v.x + v.y + v.z + v.w; }
            sum += __shfl_xor(sum, 1);
            if (hf == 0) {
                int r = o >> 3, b = o & 7;      // r = gate*4+jj; gate = o>>5 == wv
                float g = sum + lds[O_B1 + r]
                        + lds[O_WX + r * 2]     * lds[O_XS + b * 2]
                        + lds[O_WX + r * 2 + 1] * lds[O_XS + b * 2 + 1];
                lds[O_G1 + o] = (wv == 2) ? tanh_fast(g) : sigm(g);   // gate 2 = g-gate
            }
        }
        __syncthreads();

        // ---- EARLY L1 cell update + publish h1 (ack overlaps L2 reduce) ----
        if (tid < 32 && s < T) {
            int jj = tid >> 3, b = tid & 7;
            float gi = lds[O_G1 + (0 * 4 + jj) * 8 + b];
            float gf = lds[O_G1 + (1 * 4 + jj) * 8 + b];
            float gg = lds[O_G1 + (2 * 4 + jj) * 8 + b];
            float go = lds[O_G1 + (3 * 4 + jj) * 8 + b];
            float c  = gf * lds[O_C1 + tid] + gi * gg;
            lds[O_C1 + tid] = c;
            __hip_atomic_store(&h1g[p * 8192 + (bh * 8 + b) * 512 + j0 + jj],
                               go * tanh_fast(c), __ATOMIC_RELAXED, AGT);
        }

        // ---- reduce L2 + pre-activation ----
        #pragma unroll
        for (int r = 0; r < 4; ++r)
            #pragma unroll
            for (int b = 0; b < 8; ++b)
                lds[O_U + ((wv * 4 + r) * 8 + b) * 68 + ks] = a2[r][b];

        // early h1-ready flag: wave 0 drains its h1 stores (red2-write window
        // gave them time) and raises flagsA so other WGs can prestage h1_s.
        if (tid < 64 && s < T) {
            asm volatile("s_waitcnt vmcnt(0)" ::: "memory");
            if (tid == 0)
                __hip_atomic_store(&flagsA[((wg & 1) << 7) + (wg >> 1)],
                                   (unsigned)(s + 1), __ATOMIC_RELAXED, AGT);
        }
        __syncthreads();
        {
            int o = tid >> 1, hf = tid & 1;
            const float* rr = &lds[O_U + o * 68 + hf * 32];
            float sum = 0.0f;
            #pragma unroll
            for (int c = 0; c < 8; ++c) { float4 v = *(const float4*)&rr[c * 4]; sum += v.x + v.y + v.z + v.w; }
            sum += __shfl_xor(sum, 1);
            if (hf == 0) {
                float g = sum + lds[O_B2 + (o >> 3)];
                lds[O_G2 + o] = (wv == 2) ? tanh_fast(g) : sigm(g);
            }
        }
        __syncthreads();    // S6: all red-a2 reads done -> U region free

        // ---- waves 0-1: L2 cell update + publish h2 + outred fold ----
        if (tid >= 32 && tid < 64 && s >= 1) {
            int t2 = tid - 32, jj = t2 >> 3, b = t2 & 7;
            float gi = lds[O_G2 + (0 * 4 + jj) * 8 + b];
            float gf = lds[O_G2 + (1 * 4 + jj) * 8 + b];
            float gg = lds[O_G2 + (2 * 4 + jj) * 8 + b];
            float go = lds[O_G2 + (3 * 4 + jj) * 8 + b];
            float c  = gf * lds[O_C2 + t2] + gi * gg;
            lds[O_C2 + t2] = c;
            float h = go * tanh_fast(c);
            __hip_atomic_store(&h2g[p * 8192 + (bh * 8 + b) * 512 + j0 + jj],
                               h, __ATOMIC_RELAXED, AGT);
            float hn = lds[O_WO + jj] * h;
            hn += __shfl_xor(hn, 8);
            hn += __shfl_xor(hn, 16);
            if (jj == 0)
                __hip_atomic_store(&outred[p * 2048 + (bh * 8 + b) * 128 + jg],
                                   hn, __ATOMIC_RELAXED, AGT);
        }

        // ---- waves 2-3: PRE-BARRIER h1_s prestage (overlap stragglers' tails) ----
        if (tid >= 128 && s < T) {
            const unsigned long long* fA64 =
                (const unsigned long long*)flagsA + ((wg & 1) << 6);
            const unsigned tgt = (unsigned)(s + 1);
            int l = tid & 63;
            bool ok;
            do {
                unsigned long long v = __hip_atomic_load(&fA64[l], __ATOMIC_RELAXED, AGT);
                ok = ((unsigned)v >= tgt) && ((unsigned)(v >> 32) >= tgt);
                if (!__all(ok)) __builtin_amdgcn_s_sleep(1);
            } while (!__all(ok));
            const float* srcb = h1g + p * 8192 + (bh * 8) * 512 + (tid - 128) * 4;
            float4 r0, r1, r2, r3, r4, r5, r6, r7;
            STAGE8(srcb, r0, r1, r2, r3, r4, r5, r6, r7);
            const int d = (tid - 128) * 4;
            *(float4*)&lds[O_U + 0 * 1024 + d] = r0;
            *(float4*)&lds[O_U + 1 * 1024 + d] = r1;
            *(float4*)&lds[O_U + 2 * 1024 + d] = r2;
            *(float4*)&lds[O_U + 3 * 1024 + d] = r3;
            *(float4*)&lds[O_U + 4 * 1024 + d] = r4;
            *(float4*)&lds[O_U + 5 * 1024 + d] = r5;
            *(float4*)&lds[O_U + 6 * 1024 + d] = r6;
            *(float4*)&lds[O_U + 7 * 1024 + d] = r7;
        }

        gbar(flags, wg, tid, ++ph);     // half-barrier, one per superstep
    }

    // tail: y_{T-1} partials (outred parity T&1, written at s=T, covered by last bar)
    if (tid == 0) {
        const unsigned long long* row64 =
            (const unsigned long long*)(outred + (T & 1) * 2048 + bd * 128 + jh * 8);
        U64F2 v0; v0.u = __hip_atomic_load(&row64[0], __ATOMIC_RELAXED, AGT);
        U64F2 v1; v1.u = __hip_atomic_load(&row64[1], __ATOMIC_RELAXED, AGT);
        U64F2 v2; v2.u = __hip_atomic_load(&row64[2], __ATOMIC_RELAXED, AGT);
        U64F2 v3; v3.u = __hip_atomic_load(&row64[3], __ATOMIC_RELAXED, AGT);
        float sum = (v0.f[0] + v0.f[1]) + (v1.f[0] + v1.f[1])
                  + (v2.f[0] + v2.f[1]) + (v3.f[0] + v3.f[1]);
        atomicAdd(&out[bd * T + (T - 1)], sum);
    }
}

extern "C" void kernel_launch(void* const* d_in, const int* in_sizes, int n_in,
                              void* d_out, int out_size, void* d_ws, size_t ws_size,
                              hipStream_t stream) {
    const float* xin  = (const float*)d_in[0];
    const float* Wih1 = (const float*)d_in[1];
    const float* Whh1 = (const float*)d_in[2];
    const float* bih1 = (const float*)d_in[3];
    const float* bhh1 = (const float*)d_in[4];
    const float* Wih2 = (const float*)d_in[5];
    const float* Whh2 = (const float*)d_in[6];
    const float* bih2 = (const float*)d_in[7];
    const float* bhh2 = (const float*)d_in[8];
    const float* Wout = (const float*)d_in[9];
    const float* bout = (const float*)d_in[10];
    float* outp = (float*)d_out;
    int T = in_sizes[0] / 32;           // input is [16][T][2]

    unsigned* flags = (unsigned*)d_ws;                  // [B x256 | A x256]
    float* h1g    = (float*)d_ws + 4096;                // [2][16][512] (zero-init)
    float* h2g    = h1g + 16384;                        // [2][16][512] (zero-init)
    float* outredp= h2g + 16384;                        // [2][16][128]

    hipLaunchKernelGGL(ws_init_kernel, dim3(64), dim3(256), 0, stream,
                       flags, h1g, h2g, outp, bout, out_size);

    // PLAIN launch (R11/R12-validated): cooperative launch silently flakes.
    // Co-residency is structural: 134KB LDS -> 1 block/CU, grid == 256 == CUs.
    hipLaunchKernelGGL(lstm_kernel, dim3(NWG), dim3(NTHR), 0, stream,
                       xin, Wih1, Whh1, bih1, bhh1, Wih2, Whh2, bih2, bhh2,
                       Wout, bout, outp, flags, h1g, h2g, outredp, T);
}